// Round 9
// baseline (770.085 us; speedup 1.0000x reference)
//
#include <hip/hip_runtime.h>
#include <hip/hip_bf16.h>
#include <math.h>

#define DIM 64
#define BSHIFT 9
#define BNODES 512   // 1 << BSHIFT
#define MAXB 256     // max coarse buckets (N <= 131072)
#define EPT 8
#define CHUNK 2048   // EPT * 256

typedef __attribute__((ext_vector_type(8))) short bf16x8;
typedef __attribute__((ext_vector_type(4))) float f32x4;

__device__ __forceinline__ short f2bf(float x) {
    union { __hip_bfloat16 b; short s; } u;
    u.b = __float2bfloat16(x);
    return u.s;
}
__device__ __forceinline__ float bf2f(short s) {
    return __uint_as_float(((unsigned)(unsigned short)s) << 16);
}

// ---------------- CSR build: binned 2-pass sort (r6, restored) ----------------
// r8 lesson: direct-atomic scatter wrote 107MB (1.6M x 4B scattered writes
// each dirtying a 64B line across 8 XCDs -> zero coalescing, 125us). The
// binned design exists for WRITE LOCALITY: bin_scatter gives each block
// contiguous per-bucket runs; final_scatter confines writes to a ~32KB
// bucket slice per block.

__global__ void bin_count_kernel(const int* __restrict__ dst, int* __restrict__ bucket_cnt, int E) {
    __shared__ int h[MAXB];
    int t = threadIdx.x;
    h[t] = 0;
    __syncthreads();
    for (int i = blockIdx.x * blockDim.x + t; i < E; i += gridDim.x * blockDim.x)
        atomicAdd(&h[dst[i] >> BSHIFT], 1);
    __syncthreads();
    if (h[t]) atomicAdd(&bucket_cnt[t], h[t]);
}

__global__ void bucket_scan_kernel(const int* __restrict__ bucket_cnt,
                                   int* __restrict__ bucket_off, int* __restrict__ bucket_fill) {
    __shared__ int s[MAXB];
    int t = threadIdx.x;
    int v = bucket_cnt[t];
    s[t] = v;
    __syncthreads();
    for (int off = 1; off < MAXB; off <<= 1) {
        int x = (t >= off) ? s[t - off] : 0;
        __syncthreads();
        s[t] += x;
        __syncthreads();
    }
    bucket_off[t] = s[t] - v;
    bucket_fill[t] = 0;
}

__global__ __launch_bounds__(256) void bin_scatter_kernel(
    const int* __restrict__ src, const int* __restrict__ dst,
    const int* __restrict__ bucket_off, int* __restrict__ bucket_fill,
    unsigned long long* __restrict__ binned, int E) {
    __shared__ int lcnt[MAXB];
    __shared__ int lbase[MAXB];
    int t = threadIdx.x;
    lcnt[t] = 0;
    __syncthreads();
    int base = blockIdx.x * CHUNK;
    unsigned long long pair[EPT];
    int slot[EPT];
#pragma unroll
    for (int j = 0; j < EPT; j++) {
        int idx = base + j * 256 + t;
        if (idx < E) {
            int s = src[idx], d = dst[idx];
            pair[j] = ((unsigned long long)(unsigned)d << 32) | (unsigned)s;
            slot[j] = atomicAdd(&lcnt[d >> BSHIFT], 1);
        } else {
            slot[j] = -1;
        }
    }
    __syncthreads();
    int c = lcnt[t];
    if (c) lbase[t] = atomicAdd(&bucket_fill[t], c);
    __syncthreads();
#pragma unroll
    for (int j = 0; j < EPT; j++) {
        if (slot[j] >= 0) {
            int b = (int)(pair[j] >> 32) >> BSHIFT;
            binned[(size_t)bucket_off[b] + lbase[b] + slot[j]] = pair[j];
        }
    }
}

__global__ __launch_bounds__(256) void node_count_kernel(
    const unsigned long long* __restrict__ binned, const int* __restrict__ bucket_off,
    const int* __restrict__ bucket_cnt, int* __restrict__ counts, int N) {
    __shared__ int cnt[BNODES];
    int b = blockIdx.x, t = threadIdx.x;
    for (int i = t; i < BNODES; i += 256) cnt[i] = 0;
    __syncthreads();
    int s0 = bucket_off[b], c = bucket_cnt[b];
    for (int i = t; i < c; i += 256) {
        int d = (int)(binned[(size_t)s0 + i] >> 32);
        atomicAdd(&cnt[d & (BNODES - 1)], 1);
    }
    __syncthreads();
    int nbase = b << BSHIFT;
    for (int i = t; i < BNODES; i += 256)
        if (nbase + i < N) counts[nbase + i] = cnt[i];
}

__global__ void scan1_kernel(const int* __restrict__ counts, int* __restrict__ excl,
                             int* __restrict__ blk_sums, int n) {
    __shared__ int sdata[256];
    int t = threadIdx.x;
    int base = blockIdx.x * 1024 + t * 4;
    int v0 = (base + 0 < n) ? counts[base + 0] : 0;
    int v1 = (base + 1 < n) ? counts[base + 1] : 0;
    int v2 = (base + 2 < n) ? counts[base + 2] : 0;
    int v3 = (base + 3 < n) ? counts[base + 3] : 0;
    int tsum = v0 + v1 + v2 + v3;
    sdata[t] = tsum;
    __syncthreads();
    for (int off = 1; off < 256; off <<= 1) {
        int x = (t >= off) ? sdata[t - off] : 0;
        __syncthreads();
        sdata[t] += x;
        __syncthreads();
    }
    int run = sdata[t] - tsum;
    if (base + 0 < n) excl[base + 0] = run; run += v0;
    if (base + 1 < n) excl[base + 1] = run; run += v1;
    if (base + 2 < n) excl[base + 2] = run; run += v2;
    if (base + 3 < n) excl[base + 3] = run;
    if (t == 255) blk_sums[blockIdx.x] = sdata[255];
}

__global__ void scan2_kernel(int* __restrict__ blk_sums, int nb) {
    __shared__ int s[128];
    int t = threadIdx.x;
    s[t] = (t < nb) ? blk_sums[t] : 0;
    __syncthreads();
    for (int off = 1; off < 128; off <<= 1) {
        int x = (t >= off) ? s[t - off] : 0;
        __syncthreads();
        s[t] += x;
        __syncthreads();
    }
    if (t < nb) blk_sums[t] = (t > 0) ? s[t - 1] : 0;
}

__global__ void scan3_kernel(int* __restrict__ excl, const int* __restrict__ blk_sums,
                             int n, int total) {
    int i = blockIdx.x * blockDim.x + threadIdx.x;
    if (i < n) excl[i] += blk_sums[i >> 10];
    if (i == 0) excl[n] = total;
}

__global__ __launch_bounds__(256) void final_scatter_kernel(
    const unsigned long long* __restrict__ binned, const int* __restrict__ bucket_off,
    const int* __restrict__ bucket_cnt, const int* __restrict__ row_ptr,
    int* __restrict__ src_sorted, int N) {
    __shared__ int fill[BNODES];
    int b = blockIdx.x, t = threadIdx.x;
    for (int i = t; i < BNODES; i += 256) fill[i] = 0;
    __syncthreads();
    int s0 = bucket_off[b], c = bucket_cnt[b];
    for (int i = t; i < c; i += 256) {
        unsigned long long p = binned[(size_t)s0 + i];
        int d = (int)(p >> 32);
        int pos = row_ptr[d] + atomicAdd(&fill[d & (BNODES - 1)], 1);
        src_sorted[pos] = (int)(p & 0xffffffffu);
    }
}

// ---------------- per-layer kernels ----------------

// Per-layer prep (runs once, 3 blocks):
//  wl = (W @ al) * log2e, wr = (W @ ar) * log2e  (attn uses exp2 directly)
//  whi/wlo: split-precision bf16 W fragments PRE-PACKED in the gemm wave's
//  fragment layout (16x 16B loads instead of 64 scalar loads per wave).
//  frag layout: idx = ((ks*4+nt)*4+quad)*128 + li*8 + j  ->
//               W[(ks*32+quad*8+j)*64 + nt*16+li]
__global__ void wlr_kernel(
    const float* __restrict__ W1, const float* __restrict__ al1, const float* __restrict__ ar1,
    const float* __restrict__ W2, const float* __restrict__ al2, const float* __restrict__ ar2,
    const float* __restrict__ W3, const float* __restrict__ al3, const float* __restrict__ ar3,
    float* __restrict__ wlr, short* __restrict__ wfrag) {
    const float* W  = (blockIdx.x == 0) ? W1  : (blockIdx.x == 1) ? W2  : W3;
    const float* al = (blockIdx.x == 0) ? al1 : (blockIdx.x == 1) ? al2 : al3;
    const float* ar = (blockIdx.x == 0) ? ar1 : (blockIdx.x == 1) ? ar2 : ar3;
    int t = threadIdx.x;
    short* whi = wfrag + blockIdx.x * 8192;
    short* wlo = whi + 4096;
    for (int idx = t; idx < 4096; idx += 256) {
        int j = idx & 7, li = (idx >> 3) & 15, quad = (idx >> 7) & 3;
        int nt = (idx >> 9) & 3, ks = idx >> 11;
        int k = ks * 32 + quad * 8 + j, nn = nt * 16 + li;
        float w = W[k * 64 + nn];
        short hi = f2bf(w);
        whi[idx] = hi;
        wlo[idx] = f2bf(w - bf2f(hi));
    }
    if (t < 64) {
        float l = 0.f, r = 0.f;
        for (int nn = 0; nn < 64; nn++) {
            float w = W[t * 64 + nn];
            l = fmaf(w, al[nn], l);
            r = fmaf(w, ar[nn], r);
        }
        const float LOG2E = 1.4426950408889634f;
        wlr[blockIdx.x * 128 + t] = l * LOG2E;
        wlr[blockIdx.x * 128 + 64 + t] = r * LOG2E;
    }
}

// MFMA GEMM: feat(bf16) = bnelu(h) @ W ; el = act.wl ; er = act.wr
// One wave per 16-row tile. W fragments vector-loaded pre-packed (wlr_kernel).
// A-frag: A[m=lane&15][k=(lane>>4)*8+j]; B-frag: B[k=(lane>>4)*8+j][n=lane&15];
// C/D: row=(lane>>4)*4+reg, col=lane&15   [learn_hip m89-verified layouts]
__global__ __launch_bounds__(256) void gemm64_mfma_kernel(
    const float* __restrict__ h, const short* __restrict__ wfrag_l,
    const float* __restrict__ wl, const float* __restrict__ wr,
    const float* __restrict__ stats, const float* __restrict__ g,
    const float* __restrict__ beta, int do_bn, float invN,
    __hip_bfloat16* __restrict__ feat, float* __restrict__ el, float* __restrict__ er,
    int n) {
    int t = threadIdx.x;
    int lane = t & 63;
    int li = lane & 15;
    int quad = lane >> 4;
    int wv = t >> 6;

    // B fragments: 16 contiguous 16B loads (pre-packed hi/lo split)
    const short* whi = wfrag_l;
    const short* wlo = wfrag_l + 4096;
    bf16x8 b_hi[2][4], b_lo[2][4];
#pragma unroll
    for (int ks = 0; ks < 2; ks++)
#pragma unroll
        for (int nt = 0; nt < 4; nt++) {
            int base = (((ks * 4 + nt) * 4 + quad) * 16 + li) * 8;
            b_hi[ks][nt] = *(const bf16x8*)(whi + base);
            b_lo[ks][nt] = *(const bf16x8*)(wlo + base);
        }
    // wl/wr entries for the k-indices this lane's A-frag holds
    float wlv[2][8], wrv[2][8];
#pragma unroll
    for (int ks = 0; ks < 2; ks++)
#pragma unroll
        for (int j = 0; j < 8; j++) {
            wlv[ks][j] = wl[ks * 32 + quad * 8 + j];
            wrv[ks][j] = wr[ks * 32 + quad * 8 + j];
        }

    // BN scale/shift for input channels this lane touches: k = ks*32 + quad*8 + j
    float sc[2][8], sh[2][8];
    if (do_bn) {
#pragma unroll
        for (int ks = 0; ks < 2; ks++)
#pragma unroll
            for (int j = 0; j < 8; j++) {
                int k = ks * 32 + quad * 8 + j;
                float mu = stats[k] * invN;
                float var = fmaf(-mu, mu, stats[64 + k] * invN);
                float inv = rsqrtf(var + 1e-5f) * g[k];
                sc[ks][j] = inv;
                sh[ks][j] = beta[k] - mu * inv;
            }
    }

    int ntiles = (n + 15) >> 4;
    for (int tile = blockIdx.x * 4 + wv; tile < ntiles; tile += gridDim.x * 4) {
        int m0 = tile << 4;
        int rrow = m0 + li;
        const float* rowp = h + (size_t)((rrow < n) ? rrow : (n - 1)) * 64;
        bf16x8 a_hi[2], a_lo[2];
        float elp = 0.f, erp = 0.f;   // el/er partials on the f32 activations
#pragma unroll
        for (int ks = 0; ks < 2; ks++) {
            float4 v0 = *(const float4*)(rowp + ks * 32 + quad * 8);
            float4 v1 = *(const float4*)(rowp + ks * 32 + quad * 8 + 4);
            float x[8] = {v0.x, v0.y, v0.z, v0.w, v1.x, v1.y, v1.z, v1.w};
#pragma unroll
            for (int j = 0; j < 8; j++) {
                float v = x[j];
                if (do_bn) {
                    v = fmaf(v, sc[ks][j], sh[ks][j]);
                    if (v < 0.f) v = expm1f(v);   // ELU
                }
                elp = fmaf(v, wlv[ks][j], elp);
                erp = fmaf(v, wrv[ks][j], erp);
                short hi = f2bf(v);
                a_hi[ks][j] = hi;
                a_lo[ks][j] = f2bf(v - bf2f(hi));
            }
        }
        // el/er: A-frag row of this lane is m0+li; sum partials across the 4 quads
        elp += __shfl_xor(elp, 16, 64);
        elp += __shfl_xor(elp, 32, 64);
        erp += __shfl_xor(erp, 16, 64);
        erp += __shfl_xor(erp, 32, 64);
        if (lane < 16 && m0 + li < n) {
            el[m0 + li] = elp;
            er[m0 + li] = erp;
        }
        f32x4 acc[4];
#pragma unroll
        for (int nt = 0; nt < 4; nt++) acc[nt] = (f32x4){0.f, 0.f, 0.f, 0.f};
#pragma unroll
        for (int ks = 0; ks < 2; ks++)
#pragma unroll
            for (int nt = 0; nt < 4; nt++) {
                acc[nt] = __builtin_amdgcn_mfma_f32_16x16x32_bf16(a_hi[ks], b_hi[ks][nt], acc[nt], 0, 0, 0);
                acc[nt] = __builtin_amdgcn_mfma_f32_16x16x32_bf16(a_lo[ks], b_hi[ks][nt], acc[nt], 0, 0, 0);
                acc[nt] = __builtin_amdgcn_mfma_f32_16x16x32_bf16(a_hi[ks], b_lo[ks][nt], acc[nt], 0, 0, 0);
            }
        // feat store (bf16)
#pragma unroll
        for (int nt = 0; nt < 4; nt++)
#pragma unroll
            for (int reg = 0; reg < 4; reg++) {
                int wrow = m0 + quad * 4 + reg;
                if (wrow < n) {
                    union { __hip_bfloat16 b; short s; } u;
                    u.s = f2bf(acc[nt][reg]);
                    feat[(size_t)wrow * 64 + nt * 16 + li] = u.b;
                }
            }
    }
}

// Fused edge-score + softmax + weighted aggregate + BN-stats.
// FOUR nodes per wave (r6 structure): 8 edge-slots x 8 dims, 2-deep named
// ping-pong prefetch, exp2 on pre-scaled el/er, -inf masking, reduce-scatter
// epilogue. NEW (r9): each lane ends holding one output dim d (bijection),
// so BN column stats are accumulated in-register over the wave's 4 nodes,
// LDS-reduced across the block's 4 waves, and flushed as 128 atomicAdds per
// block -- deletes the 3 bn_stats launches (77MB of re-reads).
#define AGG_LOAD(P, ELV, POS)                                  \
    {                                                          \
        int idx = (POS) + q;                                   \
        bool v = idx < end;                                    \
        int idc = v ? idx : end - 1;                           \
        int sn = src_sorted[idc];                              \
        float ev = el[sn];                                     \
        ELV = v ? ev : -INFINITY;                              \
        P = featv[(size_t)sn * 8 + li];                        \
    }

#define AGG_CHUNK(P, ELV)                                      \
    {                                                          \
        float e = ELV + er_n;                                  \
        e = fmaxf(e, 0.2f * e);                                \
        float w = exp2f(e);                                    \
        s += w;                                                \
        a0 = fmaf(w, __uint_as_float(P.x << 16), a0);          \
        a1 = fmaf(w, __uint_as_float(P.x & 0xffff0000u), a1);  \
        a2 = fmaf(w, __uint_as_float(P.y << 16), a2);          \
        a3 = fmaf(w, __uint_as_float(P.y & 0xffff0000u), a3);  \
        a4 = fmaf(w, __uint_as_float(P.z << 16), a4);          \
        a5 = fmaf(w, __uint_as_float(P.z & 0xffff0000u), a5);  \
        a6 = fmaf(w, __uint_as_float(P.w << 16), a6);          \
        a7 = fmaf(w, __uint_as_float(P.w & 0xffff0000u), a7);  \
    }

__global__ __launch_bounds__(256) void attn_agg_kernel(
    const int* __restrict__ row_ptr, const int* __restrict__ src_sorted,
    const float* __restrict__ el, const float* __restrict__ er,
    const __hip_bfloat16* __restrict__ feat, const float* __restrict__ bias,
    float* __restrict__ out, float* __restrict__ stats, int n) {
    __shared__ float ls[256], lss[256];
    int t = threadIdx.x, lane = t & 63;
    int q = lane >> 3;        // edge slot 0..7
    int li = lane & 7;        // dim octet 0..7
    int d = li * 8 + ((q & 1) << 2) + (q & 2) + ((q >> 2) & 1);  // this lane's dim
    float bias_d = bias[d];
    int node0 = blockIdx.x * 16 + (t >> 6) * 4;   // 4 nodes per wave
    const uint4* featv = (const uint4*)feat;

    float sacc = 0.f, ssacc = 0.f;                // BN stats partials (dim d)

#pragma unroll
    for (int j = 0; j < 4; j++) {
        int node = node0 + j;
        if (node >= n) break;                      // wave-uniform
        int start = row_ptr[node], end = row_ptr[node + 1];
        float er_n = er[node];

        float s = 0.f;
        float a0 = 0.f, a1 = 0.f, a2 = 0.f, a3 = 0.f;
        float a4 = 0.f, a5 = 0.f, a6 = 0.f, a7 = 0.f;

        uint4 pA = {0u, 0u, 0u, 0u}, pB = {0u, 0u, 0u, 0u};
        float elA = -INFINITY, elB = -INFINITY;
        if (start < end) AGG_LOAD(pA, elA, start)
        if (start + 8 < end) AGG_LOAD(pB, elB, start + 8)
        for (int i = start; i < end; i += 16) {    // all branches wave-uniform
            AGG_CHUNK(pA, elA)
            if (i + 16 < end) AGG_LOAD(pA, elA, i + 16)
            if (i + 8 < end) {
                AGG_CHUNK(pB, elB)
                if (i + 24 < end) AGG_LOAD(pB, elB, i + 24)
            }
        }
        // s: full butterfly over slots (all lanes need inv_s)
        s += __shfl_xor(s, 8, 64);
        s += __shfl_xor(s, 16, 64);
        s += __shfl_xor(s, 32, 64);
        // reduce-scatter: lane (q,li) ends with dim d
        bool b0 = (q & 1) != 0;
        float t0 = __shfl_xor(a0, 8, 64), t1 = __shfl_xor(a1, 8, 64);
        float t2 = __shfl_xor(a2, 8, 64), t3 = __shfl_xor(a3, 8, 64);
        float t4 = __shfl_xor(a4, 8, 64), t5 = __shfl_xor(a5, 8, 64);
        float t6 = __shfl_xor(a6, 8, 64), t7 = __shfl_xor(a7, 8, 64);
        float x0 = b0 ? (a4 + t4) : (a0 + t0);
        float x1 = b0 ? (a5 + t5) : (a1 + t1);
        float y0 = b0 ? (a6 + t6) : (a2 + t2);
        float y1 = b0 ? (a7 + t7) : (a3 + t3);
        bool b1 = (q & 2) != 0;
        float u0 = __shfl_xor(x0, 16, 64), u1 = __shfl_xor(x1, 16, 64);
        float v0 = __shfl_xor(y0, 16, 64), v1 = __shfl_xor(y1, 16, 64);
        float z0 = b1 ? (y0 + v0) : (x0 + u0);
        float z1 = b1 ? (y1 + v1) : (x1 + u1);
        z0 += __shfl_xor(z0, 32, 64);
        z1 += __shfl_xor(z1, 32, 64);
        float val = ((q & 4) != 0) ? z1 : z0;
        float inv_s = (s > 0.f) ? 1.f / s : 0.f;
        float x = fmaf(val, inv_s, bias_d);
        out[(size_t)node * 64 + d] = x;
        sacc += x;
        ssacc = fmaf(x, x, ssacc);
    }

    // BN stats: reduce the 4 waves' partials (same lane -> same dim), then
    // one atomicAdd pair per dim per block.
    ls[t] = sacc;
    lss[t] = ssacc;
    __syncthreads();
    if (t < 64) {
        float a = ls[t] + ls[t + 64] + ls[t + 128] + ls[t + 192];
        float b = lss[t] + lss[t + 64] + lss[t + 128] + lss[t + 192];
        int q0 = t >> 3, li0 = t & 7;
        int d0 = li0 * 8 + ((q0 & 1) << 2) + (q0 & 2) + ((q0 >> 2) & 1);
        atomicAdd(&stats[d0], a);
        atomicAdd(&stats[64 + d0], b);
    }
}

__global__ void bn_apply_kernel(float* __restrict__ h, const float* __restrict__ stats,
                                const float* __restrict__ g, const float* __restrict__ beta,
                                int n, int do_elu) {
    int i = blockIdx.x * blockDim.x + threadIdx.x;
    int total = n * DIM;
    int stride = gridDim.x * blockDim.x;
    float invN = 1.f / (float)n;
    for (; i < total; i += stride) {
        int c = i & 63;
        float mu = stats[c] * invN;
        float var = fmaf(-mu, mu, stats[DIM + c] * invN);
        float x = (h[i] - mu) * rsqrtf(var + 1e-5f) * g[c] + beta[c];
        if (do_elu && x < 0.f) x = expm1f(x);
        h[i] = x;
    }
}

// ---------------- launch ----------------

extern "C" void kernel_launch(void* const* d_in, const int* in_sizes, int n_in,
                              void* d_out, int out_size, void* d_ws, size_t ws_size,
                              hipStream_t stream) {
    const float* nw = (const float*)d_in[0];
    const int* src = (const int*)d_in[2];
    const int* dst = (const int*)d_in[3];
    const int N = in_sizes[0] / DIM;
    const int E = in_sizes[2];
    const float invN = 1.f / (float)N;
    const int nbuck = (N + BNODES - 1) >> BSHIFT;

    char* ws = (char*)d_ws;
    size_t off = 0;
    auto alloc = [&](size_t bytes) -> void* {
        void* p = ws + off;
        off += (bytes + 255) & ~(size_t)255;
        return p;
    };
    int* counts       = (int*)alloc((size_t)N * 4);
    int* row_ptr      = (int*)alloc(((size_t)N + 1) * 4);
    int* blk_sums     = (int*)alloc(512);
    int* bucket_cnt   = (int*)alloc(MAXB * 4);
    int* bucket_off   = (int*)alloc(MAXB * 4);
    int* bucket_fill  = (int*)alloc(MAXB * 4);
    unsigned long long* binned = (unsigned long long*)alloc((size_t)E * 8);
    int* src_sorted   = (int*)alloc((size_t)E * 4);
    float* el         = (float*)alloc((size_t)N * 4);
    float* er         = (float*)alloc((size_t)N * 4);
    __hip_bfloat16* feat = (__hip_bfloat16*)alloc((size_t)N * DIM * 2);
    float* hbuf       = (float*)alloc((size_t)N * DIM * 4);
    float* stats      = (float*)alloc(3 * 512);     // 3 layer slots of 128 floats
    float* wlr        = (float*)alloc(3 * 128 * 4);
    short* wfrag      = (short*)alloc(3 * 8192 * 2); // [layer][hi/lo][4096] bf16

    int nb = (N + 1023) / 1024;
    int ntiles = (N + 15) >> 4;

    // CSR build (binned, once; same graph for all 3 layers) + per-layer W prep
    hipMemsetAsync(bucket_cnt, 0, MAXB * 4, stream);
    hipMemsetAsync(stats, 0, 3 * 512, stream);
    wlr_kernel<<<3, 256, 0, stream>>>(
        (const float*)d_in[4],  (const float*)d_in[5],  (const float*)d_in[6],
        (const float*)d_in[10], (const float*)d_in[11], (const float*)d_in[12],
        (const float*)d_in[16], (const float*)d_in[17], (const float*)d_in[18],
        wlr, wfrag);
    bin_count_kernel<<<256, 256, 0, stream>>>(dst, bucket_cnt, E);
    bucket_scan_kernel<<<1, MAXB, 0, stream>>>(bucket_cnt, bucket_off, bucket_fill);
    bin_scatter_kernel<<<(E + CHUNK - 1) / CHUNK, 256, 0, stream>>>(
        src, dst, bucket_off, bucket_fill, binned, E);
    node_count_kernel<<<nbuck, 256, 0, stream>>>(binned, bucket_off, bucket_cnt, counts, N);
    scan1_kernel<<<nb, 256, 0, stream>>>(counts, row_ptr, blk_sums, N);
    scan2_kernel<<<1, 128, 0, stream>>>(blk_sums, nb);
    scan3_kernel<<<(N + 255) / 256, 256, 0, stream>>>(row_ptr, blk_sums, N, E);
    final_scatter_kernel<<<nbuck, 256, 0, stream>>>(binned, bucket_off, bucket_cnt,
                                                    row_ptr, src_sorted, N);

    for (int l = 0; l < 3; l++) {
        const float* b    = (const float*)d_in[7 + 6 * l];
        const float* hin = (l == 0) ? nw : hbuf;
        float* hout = (l == 2) ? (float*)d_out : hbuf;
        float* stats_prev = (l == 0) ? stats : stats + (l - 1) * 128;
        float* stats_cur  = stats + l * 128;

        gemm64_mfma_kernel<<<(ntiles + 3) / 4, 256, 0, stream>>>(
            hin, wfrag + l * 8192,
            wlr + l * 128, wlr + l * 128 + 64,
            stats_prev,
            (l == 0) ? (const float*)d_in[8] : (const float*)d_in[8 + 6 * (l - 1)],
            (l == 0) ? (const float*)d_in[9] : (const float*)d_in[9 + 6 * (l - 1)],
            (l > 0) ? 1 : 0, invN,
            feat, el, er, N);
        attn_agg_kernel<<<(N + 15) / 16, 256, 0, stream>>>(row_ptr, src_sorted, el, er,
                                                           feat, b, hout, stats_cur, N);
    }
    // final BatchNorm (no ELU) on d_out
    bn_apply_kernel<<<2048, 256, 0, stream>>>((float*)d_out, stats + 2 * 128,
                                              (const float*)d_in[8 + 12],
                                              (const float*)d_in[9 + 12],
                                              N, 0);
}

// Round 10
// 483.209 us; speedup vs baseline: 1.5937x; 1.5937x over previous
//
#include <hip/hip_runtime.h>
#include <hip/hip_bf16.h>
#include <math.h>

#define DIM 64
#define BSHIFT 9
#define BNODES 512   // 1 << BSHIFT
#define MAXB 256     // max coarse buckets (N <= 131072)
#define EPT 8
#define CHUNK 2048   // EPT * 256

typedef __attribute__((ext_vector_type(8))) short bf16x8;
typedef __attribute__((ext_vector_type(4))) float f32x4;

__device__ __forceinline__ short f2bf(float x) {
    union { __hip_bfloat16 b; short s; } u;
    u.b = __float2bfloat16(x);
    return u.s;
}
__device__ __forceinline__ float bf2f(short s) {
    return __uint_as_float(((unsigned)(unsigned short)s) << 16);
}

// ---------------- CSR build: binned 2-pass sort ----------------
// r8 lesson: direct-atomic scatter wrote 107MB (1.6M x 4B scattered writes
// each dirtying a 64B line across 8 XCDs -> zero coalescing, 125us). The
// binned design exists for WRITE LOCALITY.

__global__ void bin_count_kernel(const int* __restrict__ dst, int* __restrict__ bucket_cnt, int E) {
    __shared__ int h[MAXB];
    int t = threadIdx.x;
    h[t] = 0;
    __syncthreads();
    for (int i = blockIdx.x * blockDim.x + t; i < E; i += gridDim.x * blockDim.x)
        atomicAdd(&h[dst[i] >> BSHIFT], 1);
    __syncthreads();
    if (h[t]) atomicAdd(&bucket_cnt[t], h[t]);
}

__global__ void bucket_scan_kernel(const int* __restrict__ bucket_cnt,
                                   int* __restrict__ bucket_off, int* __restrict__ bucket_fill) {
    __shared__ int s[MAXB];
    int t = threadIdx.x;
    int v = bucket_cnt[t];
    s[t] = v;
    __syncthreads();
    for (int off = 1; off < MAXB; off <<= 1) {
        int x = (t >= off) ? s[t - off] : 0;
        __syncthreads();
        s[t] += x;
        __syncthreads();
    }
    bucket_off[t] = s[t] - v;
    bucket_fill[t] = 0;
}

__global__ __launch_bounds__(256) void bin_scatter_kernel(
    const int* __restrict__ src, const int* __restrict__ dst,
    const int* __restrict__ bucket_off, int* __restrict__ bucket_fill,
    unsigned long long* __restrict__ binned, int E) {
    __shared__ int lcnt[MAXB];
    __shared__ int lbase[MAXB];
    int t = threadIdx.x;
    lcnt[t] = 0;
    __syncthreads();
    int base = blockIdx.x * CHUNK;
    unsigned long long pair[EPT];
    int slot[EPT];
#pragma unroll
    for (int j = 0; j < EPT; j++) {
        int idx = base + j * 256 + t;
        if (idx < E) {
            int s = src[idx], d = dst[idx];
            pair[j] = ((unsigned long long)(unsigned)d << 32) | (unsigned)s;
            slot[j] = atomicAdd(&lcnt[d >> BSHIFT], 1);
        } else {
            slot[j] = -1;
        }
    }
    __syncthreads();
    int c = lcnt[t];
    if (c) lbase[t] = atomicAdd(&bucket_fill[t], c);
    __syncthreads();
#pragma unroll
    for (int j = 0; j < EPT; j++) {
        if (slot[j] >= 0) {
            int b = (int)(pair[j] >> 32) >> BSHIFT;
            binned[(size_t)bucket_off[b] + lbase[b] + slot[j]] = pair[j];
        }
    }
}

__global__ __launch_bounds__(256) void node_count_kernel(
    const unsigned long long* __restrict__ binned, const int* __restrict__ bucket_off,
    const int* __restrict__ bucket_cnt, int* __restrict__ counts, int N) {
    __shared__ int cnt[BNODES];
    int b = blockIdx.x, t = threadIdx.x;
    for (int i = t; i < BNODES; i += 256) cnt[i] = 0;
    __syncthreads();
    int s0 = bucket_off[b], c = bucket_cnt[b];
    for (int i = t; i < c; i += 256) {
        int d = (int)(binned[(size_t)s0 + i] >> 32);
        atomicAdd(&cnt[d & (BNODES - 1)], 1);
    }
    __syncthreads();
    int nbase = b << BSHIFT;
    for (int i = t; i < BNODES; i += 256)
        if (nbase + i < N) counts[nbase + i] = cnt[i];
}

__global__ void scan1_kernel(const int* __restrict__ counts, int* __restrict__ excl,
                             int* __restrict__ blk_sums, int n) {
    __shared__ int sdata[256];
    int t = threadIdx.x;
    int base = blockIdx.x * 1024 + t * 4;
    int v0 = (base + 0 < n) ? counts[base + 0] : 0;
    int v1 = (base + 1 < n) ? counts[base + 1] : 0;
    int v2 = (base + 2 < n) ? counts[base + 2] : 0;
    int v3 = (base + 3 < n) ? counts[base + 3] : 0;
    int tsum = v0 + v1 + v2 + v3;
    sdata[t] = tsum;
    __syncthreads();
    for (int off = 1; off < 256; off <<= 1) {
        int x = (t >= off) ? sdata[t - off] : 0;
        __syncthreads();
        sdata[t] += x;
        __syncthreads();
    }
    int run = sdata[t] - tsum;
    if (base + 0 < n) excl[base + 0] = run; run += v0;
    if (base + 1 < n) excl[base + 1] = run; run += v1;
    if (base + 2 < n) excl[base + 2] = run; run += v2;
    if (base + 3 < n) excl[base + 3] = run;
    if (t == 255) blk_sums[blockIdx.x] = sdata[255];
}

__global__ void scan2_kernel(int* __restrict__ blk_sums, int nb) {
    __shared__ int s[128];
    int t = threadIdx.x;
    s[t] = (t < nb) ? blk_sums[t] : 0;
    __syncthreads();
    for (int off = 1; off < 128; off <<= 1) {
        int x = (t >= off) ? s[t - off] : 0;
        __syncthreads();
        s[t] += x;
        __syncthreads();
    }
    if (t < nb) blk_sums[t] = (t > 0) ? s[t - 1] : 0;
}

__global__ void scan3_kernel(int* __restrict__ excl, const int* __restrict__ blk_sums,
                             int n, int total) {
    int i = blockIdx.x * blockDim.x + threadIdx.x;
    if (i < n) excl[i] += blk_sums[i >> 10];
    if (i == 0) excl[n] = total;
}

__global__ __launch_bounds__(256) void final_scatter_kernel(
    const unsigned long long* __restrict__ binned, const int* __restrict__ bucket_off,
    const int* __restrict__ bucket_cnt, const int* __restrict__ row_ptr,
    int* __restrict__ src_sorted, int N) {
    __shared__ int fill[BNODES];
    int b = blockIdx.x, t = threadIdx.x;
    for (int i = t; i < BNODES; i += 256) fill[i] = 0;
    __syncthreads();
    int s0 = bucket_off[b], c = bucket_cnt[b];
    for (int i = t; i < c; i += 256) {
        unsigned long long p = binned[(size_t)s0 + i];
        int d = (int)(p >> 32);
        int pos = row_ptr[d] + atomicAdd(&fill[d & (BNODES - 1)], 1);
        src_sorted[pos] = (int)(p & 0xffffffffu);
    }
}

// ---------------- per-layer kernels ----------------

// Per-layer prep (runs once, 3 blocks): wl/wr = (W@al/ar)*log2e, plus
// pre-packed hi/lo split-bf16 W fragments in the gemm wave's layout.
__global__ void wlr_kernel(
    const float* __restrict__ W1, const float* __restrict__ al1, const float* __restrict__ ar1,
    const float* __restrict__ W2, const float* __restrict__ al2, const float* __restrict__ ar2,
    const float* __restrict__ W3, const float* __restrict__ al3, const float* __restrict__ ar3,
    float* __restrict__ wlr, short* __restrict__ wfrag) {
    const float* W  = (blockIdx.x == 0) ? W1  : (blockIdx.x == 1) ? W2  : W3;
    const float* al = (blockIdx.x == 0) ? al1 : (blockIdx.x == 1) ? al2 : al3;
    const float* ar = (blockIdx.x == 0) ? ar1 : (blockIdx.x == 1) ? ar2 : ar3;
    int t = threadIdx.x;
    short* whi = wfrag + blockIdx.x * 8192;
    short* wlo = whi + 4096;
    for (int idx = t; idx < 4096; idx += 256) {
        int j = idx & 7, li = (idx >> 3) & 15, quad = (idx >> 7) & 3;
        int nt = (idx >> 9) & 3, ks = idx >> 11;
        int k = ks * 32 + quad * 8 + j, nn = nt * 16 + li;
        float w = W[k * 64 + nn];
        short hi = f2bf(w);
        whi[idx] = hi;
        wlo[idx] = f2bf(w - bf2f(hi));
    }
    if (t < 64) {
        float l = 0.f, r = 0.f;
        for (int nn = 0; nn < 64; nn++) {
            float w = W[t * 64 + nn];
            l = fmaf(w, al[nn], l);
            r = fmaf(w, ar[nn], r);
        }
        const float LOG2E = 1.4426950408889634f;
        wlr[blockIdx.x * 128 + t] = l * LOG2E;
        wlr[blockIdx.x * 128 + 64 + t] = r * LOG2E;
    }
}

// MFMA GEMM: feat(bf16) = bnelu(h) @ W ; el = act.wl ; er = act.wr
__global__ __launch_bounds__(256) void gemm64_mfma_kernel(
    const float* __restrict__ h, const short* __restrict__ wfrag_l,
    const float* __restrict__ wl, const float* __restrict__ wr,
    const float* __restrict__ stats, const float* __restrict__ g,
    const float* __restrict__ beta, int do_bn, float invN,
    __hip_bfloat16* __restrict__ feat, float* __restrict__ el, float* __restrict__ er,
    int n) {
    int t = threadIdx.x;
    int lane = t & 63;
    int li = lane & 15;
    int quad = lane >> 4;
    int wv = t >> 6;

    const short* whi = wfrag_l;
    const short* wlo = wfrag_l + 4096;
    bf16x8 b_hi[2][4], b_lo[2][4];
#pragma unroll
    for (int ks = 0; ks < 2; ks++)
#pragma unroll
        for (int nt = 0; nt < 4; nt++) {
            int base = (((ks * 4 + nt) * 4 + quad) * 16 + li) * 8;
            b_hi[ks][nt] = *(const bf16x8*)(whi + base);
            b_lo[ks][nt] = *(const bf16x8*)(wlo + base);
        }
    float wlv[2][8], wrv[2][8];
#pragma unroll
    for (int ks = 0; ks < 2; ks++)
#pragma unroll
        for (int j = 0; j < 8; j++) {
            wlv[ks][j] = wl[ks * 32 + quad * 8 + j];
            wrv[ks][j] = wr[ks * 32 + quad * 8 + j];
        }

    float sc[2][8], sh[2][8];
    if (do_bn) {
#pragma unroll
        for (int ks = 0; ks < 2; ks++)
#pragma unroll
            for (int j = 0; j < 8; j++) {
                int k = ks * 32 + quad * 8 + j;
                float mu = stats[k] * invN;
                float var = fmaf(-mu, mu, stats[64 + k] * invN);
                float inv = rsqrtf(var + 1e-5f) * g[k];
                sc[ks][j] = inv;
                sh[ks][j] = beta[k] - mu * inv;
            }
    }

    int ntiles = (n + 15) >> 4;
    for (int tile = blockIdx.x * 4 + wv; tile < ntiles; tile += gridDim.x * 4) {
        int m0 = tile << 4;
        int rrow = m0 + li;
        const float* rowp = h + (size_t)((rrow < n) ? rrow : (n - 1)) * 64;
        bf16x8 a_hi[2], a_lo[2];
        float elp = 0.f, erp = 0.f;
#pragma unroll
        for (int ks = 0; ks < 2; ks++) {
            float4 v0 = *(const float4*)(rowp + ks * 32 + quad * 8);
            float4 v1 = *(const float4*)(rowp + ks * 32 + quad * 8 + 4);
            float x[8] = {v0.x, v0.y, v0.z, v0.w, v1.x, v1.y, v1.z, v1.w};
#pragma unroll
            for (int j = 0; j < 8; j++) {
                float v = x[j];
                if (do_bn) {
                    v = fmaf(v, sc[ks][j], sh[ks][j]);
                    if (v < 0.f) v = expm1f(v);   // ELU
                }
                elp = fmaf(v, wlv[ks][j], elp);
                erp = fmaf(v, wrv[ks][j], erp);
                short hi = f2bf(v);
                a_hi[ks][j] = hi;
                a_lo[ks][j] = f2bf(v - bf2f(hi));
            }
        }
        elp += __shfl_xor(elp, 16, 64);
        elp += __shfl_xor(elp, 32, 64);
        erp += __shfl_xor(erp, 16, 64);
        erp += __shfl_xor(erp, 32, 64);
        if (lane < 16 && m0 + li < n) {
            el[m0 + li] = elp;
            er[m0 + li] = erp;
        }
        f32x4 acc[4];
#pragma unroll
        for (int nt = 0; nt < 4; nt++) acc[nt] = (f32x4){0.f, 0.f, 0.f, 0.f};
#pragma unroll
        for (int ks = 0; ks < 2; ks++)
#pragma unroll
            for (int nt = 0; nt < 4; nt++) {
                acc[nt] = __builtin_amdgcn_mfma_f32_16x16x32_bf16(a_hi[ks], b_hi[ks][nt], acc[nt], 0, 0, 0);
                acc[nt] = __builtin_amdgcn_mfma_f32_16x16x32_bf16(a_lo[ks], b_hi[ks][nt], acc[nt], 0, 0, 0);
                acc[nt] = __builtin_amdgcn_mfma_f32_16x16x32_bf16(a_hi[ks], b_lo[ks][nt], acc[nt], 0, 0, 0);
            }
#pragma unroll
        for (int nt = 0; nt < 4; nt++)
#pragma unroll
            for (int reg = 0; reg < 4; reg++) {
                int wrow = m0 + quad * 4 + reg;
                if (wrow < n) {
                    union { __hip_bfloat16 b; short s; } u;
                    u.s = f2bf(acc[nt][reg]);
                    feat[(size_t)wrow * 64 + nt * 16 + li] = u.b;
                }
            }
    }
}

// Fused edge-score + softmax + weighted aggregate + BN-stats partials.
// FOUR nodes per wave (r6 structure). r10: BN stats accumulated in-register
// per lane (each lane owns one dim d, bijection), LDS-reduced across the 4
// waves, then written NON-ATOMICALLY as a 128-float per-block partial.
// r9 lesson: 6250 blocks x 128 atomicAdds to the same 128 addresses =
// 6250-deep serialization per address at L2 (+120us). Partials + a 64-block
// reduce keeps contention at the proven-cheap level (64/address).
#define AGG_LOAD(P, ELV, POS)                                  \
    {                                                          \
        int idx = (POS) + q;                                   \
        bool v = idx < end;                                    \
        int idc = v ? idx : end - 1;                           \
        int sn = src_sorted[idc];                              \
        float ev = el[sn];                                     \
        ELV = v ? ev : -INFINITY;                              \
        P = featv[(size_t)sn * 8 + li];                        \
    }

#define AGG_CHUNK(P, ELV)                                      \
    {                                                          \
        float e = ELV + er_n;                                  \
        e = fmaxf(e, 0.2f * e);                                \
        float w = exp2f(e);                                    \
        s += w;                                                \
        a0 = fmaf(w, __uint_as_float(P.x << 16), a0);          \
        a1 = fmaf(w, __uint_as_float(P.x & 0xffff0000u), a1);  \
        a2 = fmaf(w, __uint_as_float(P.y << 16), a2);          \
        a3 = fmaf(w, __uint_as_float(P.y & 0xffff0000u), a3);  \
        a4 = fmaf(w, __uint_as_float(P.z << 16), a4);          \
        a5 = fmaf(w, __uint_as_float(P.z & 0xffff0000u), a5);  \
        a6 = fmaf(w, __uint_as_float(P.w << 16), a6);          \
        a7 = fmaf(w, __uint_as_float(P.w & 0xffff0000u), a7);  \
    }

__global__ __launch_bounds__(256) void attn_agg_kernel(
    const int* __restrict__ row_ptr, const int* __restrict__ src_sorted,
    const float* __restrict__ el, const float* __restrict__ er,
    const __hip_bfloat16* __restrict__ feat, const float* __restrict__ bias,
    float* __restrict__ out, float* __restrict__ partial, int n) {
    __shared__ float ls[256], lss[256];
    int t = threadIdx.x, lane = t & 63;
    int q = lane >> 3;        // edge slot 0..7
    int li = lane & 7;        // dim octet 0..7
    int d = li * 8 + ((q & 1) << 2) + (q & 2) + ((q >> 2) & 1);  // this lane's dim
    float bias_d = bias[d];
    int node0 = blockIdx.x * 16 + (t >> 6) * 4;   // 4 nodes per wave
    const uint4* featv = (const uint4*)feat;

    float sacc = 0.f, ssacc = 0.f;                // BN stats partials (dim d)

#pragma unroll
    for (int j = 0; j < 4; j++) {
        int node = node0 + j;
        if (node >= n) break;                      // wave-uniform
        int start = row_ptr[node], end = row_ptr[node + 1];
        float er_n = er[node];

        float s = 0.f;
        float a0 = 0.f, a1 = 0.f, a2 = 0.f, a3 = 0.f;
        float a4 = 0.f, a5 = 0.f, a6 = 0.f, a7 = 0.f;

        uint4 pA = {0u, 0u, 0u, 0u}, pB = {0u, 0u, 0u, 0u};
        float elA = -INFINITY, elB = -INFINITY;
        if (start < end) AGG_LOAD(pA, elA, start)
        if (start + 8 < end) AGG_LOAD(pB, elB, start + 8)
        for (int i = start; i < end; i += 16) {    // all branches wave-uniform
            AGG_CHUNK(pA, elA)
            if (i + 16 < end) AGG_LOAD(pA, elA, i + 16)
            if (i + 8 < end) {
                AGG_CHUNK(pB, elB)
                if (i + 24 < end) AGG_LOAD(pB, elB, i + 24)
            }
        }
        s += __shfl_xor(s, 8, 64);
        s += __shfl_xor(s, 16, 64);
        s += __shfl_xor(s, 32, 64);
        bool b0 = (q & 1) != 0;
        float t0 = __shfl_xor(a0, 8, 64), t1 = __shfl_xor(a1, 8, 64);
        float t2 = __shfl_xor(a2, 8, 64), t3 = __shfl_xor(a3, 8, 64);
        float t4 = __shfl_xor(a4, 8, 64), t5 = __shfl_xor(a5, 8, 64);
        float t6 = __shfl_xor(a6, 8, 64), t7 = __shfl_xor(a7, 8, 64);
        float x0 = b0 ? (a4 + t4) : (a0 + t0);
        float x1 = b0 ? (a5 + t5) : (a1 + t1);
        float y0 = b0 ? (a6 + t6) : (a2 + t2);
        float y1 = b0 ? (a7 + t7) : (a3 + t3);
        bool b1 = (q & 2) != 0;
        float u0 = __shfl_xor(x0, 16, 64), u1 = __shfl_xor(x1, 16, 64);
        float v0 = __shfl_xor(y0, 16, 64), v1 = __shfl_xor(y1, 16, 64);
        float z0 = b1 ? (y0 + v0) : (x0 + u0);
        float z1 = b1 ? (y1 + v1) : (x1 + u1);
        z0 += __shfl_xor(z0, 32, 64);
        z1 += __shfl_xor(z1, 32, 64);
        float val = ((q & 4) != 0) ? z1 : z0;
        float inv_s = (s > 0.f) ? 1.f / s : 0.f;
        float x = fmaf(val, inv_s, bias_d);
        out[(size_t)node * 64 + d] = x;
        sacc += x;
        ssacc = fmaf(x, x, ssacc);
    }

    // BN stats: reduce 4 waves' partials (same lane -> same dim), then one
    // NON-ATOMIC coalesced 128-float partial per block.
    ls[t] = sacc;
    lss[t] = ssacc;
    __syncthreads();
    if (t < 64) {
        float a = ls[t] + ls[t + 64] + ls[t + 128] + ls[t + 192];
        float b = lss[t] + lss[t + 64] + lss[t + 128] + lss[t + 192];
        int q0 = t >> 3, li0 = t & 7;
        int d0 = li0 * 8 + ((q0 & 1) << 2) + (q0 & 2) + ((q0 >> 2) & 1);
        partial[(size_t)blockIdx.x * 128 + d0] = a;
        partial[(size_t)blockIdx.x * 128 + 64 + d0] = b;
    }
}

// Column-sum the per-block partials: 64 blocks -> 64 atomics/address (cheap).
__global__ __launch_bounds__(128) void bn_reduce_kernel(
    const float* __restrict__ partial, float* __restrict__ stats, int nblk) {
    int t = threadIdx.x;   // 0..127
    float s = 0.f;
    for (int b = blockIdx.x; b < nblk; b += gridDim.x)
        s += partial[(size_t)b * 128 + t];
    atomicAdd(&stats[t], s);
}

__global__ void bn_apply_kernel(float* __restrict__ h, const float* __restrict__ stats,
                                const float* __restrict__ g, const float* __restrict__ beta,
                                int n, int do_elu) {
    int i = blockIdx.x * blockDim.x + threadIdx.x;
    int total = n * DIM;
    int stride = gridDim.x * blockDim.x;
    float invN = 1.f / (float)n;
    for (; i < total; i += stride) {
        int c = i & 63;
        float mu = stats[c] * invN;
        float var = fmaf(-mu, mu, stats[DIM + c] * invN);
        float x = (h[i] - mu) * rsqrtf(var + 1e-5f) * g[c] + beta[c];
        if (do_elu && x < 0.f) x = expm1f(x);
        h[i] = x;
    }
}

// ---------------- launch ----------------

extern "C" void kernel_launch(void* const* d_in, const int* in_sizes, int n_in,
                              void* d_out, int out_size, void* d_ws, size_t ws_size,
                              hipStream_t stream) {
    const float* nw = (const float*)d_in[0];
    const int* src = (const int*)d_in[2];
    const int* dst = (const int*)d_in[3];
    const int N = in_sizes[0] / DIM;
    const int E = in_sizes[2];
    const float invN = 1.f / (float)N;
    const int nbuck = (N + BNODES - 1) >> BSHIFT;

    char* ws = (char*)d_ws;
    size_t off = 0;
    auto alloc = [&](size_t bytes) -> void* {
        void* p = ws + off;
        off += (bytes + 255) & ~(size_t)255;
        return p;
    };
    int* counts       = (int*)alloc((size_t)N * 4);
    int* row_ptr      = (int*)alloc(((size_t)N + 1) * 4);
    int* blk_sums     = (int*)alloc(512);
    int* bucket_cnt   = (int*)alloc(MAXB * 4);
    int* bucket_off   = (int*)alloc(MAXB * 4);
    int* bucket_fill  = (int*)alloc(MAXB * 4);
    unsigned long long* binned = (unsigned long long*)alloc((size_t)E * 8);
    int* src_sorted   = (int*)alloc((size_t)E * 4);
    float* el         = (float*)alloc((size_t)N * 4);
    float* er         = (float*)alloc((size_t)N * 4);
    __hip_bfloat16* feat = (__hip_bfloat16*)alloc((size_t)N * DIM * 2);
    float* hbuf       = (float*)alloc((size_t)N * DIM * 4);
    float* stats      = (float*)alloc(3 * 512);     // 3 layer slots of 128 floats
    float* wlr        = (float*)alloc(3 * 128 * 4);
    short* wfrag      = (short*)alloc(3 * 8192 * 2); // [layer][hi/lo][4096] bf16
    int nblk_attn     = (N + 15) / 16;
    float* partial    = (float*)alloc((size_t)nblk_attn * 128 * 4);

    int nb = (N + 1023) / 1024;
    int ntiles = (N + 15) >> 4;

    // CSR build (binned, once; same graph for all 3 layers) + per-layer W prep
    hipMemsetAsync(bucket_cnt, 0, MAXB * 4, stream);
    hipMemsetAsync(stats, 0, 3 * 512, stream);
    wlr_kernel<<<3, 256, 0, stream>>>(
        (const float*)d_in[4],  (const float*)d_in[5],  (const float*)d_in[6],
        (const float*)d_in[10], (const float*)d_in[11], (const float*)d_in[12],
        (const float*)d_in[16], (const float*)d_in[17], (const float*)d_in[18],
        wlr, wfrag);
    bin_count_kernel<<<256, 256, 0, stream>>>(dst, bucket_cnt, E);
    bucket_scan_kernel<<<1, MAXB, 0, stream>>>(bucket_cnt, bucket_off, bucket_fill);
    bin_scatter_kernel<<<(E + CHUNK - 1) / CHUNK, 256, 0, stream>>>(
        src, dst, bucket_off, bucket_fill, binned, E);
    node_count_kernel<<<nbuck, 256, 0, stream>>>(binned, bucket_off, bucket_cnt, counts, N);
    scan1_kernel<<<nb, 256, 0, stream>>>(counts, row_ptr, blk_sums, N);
    scan2_kernel<<<1, 128, 0, stream>>>(blk_sums, nb);
    scan3_kernel<<<(N + 255) / 256, 256, 0, stream>>>(row_ptr, blk_sums, N, E);
    final_scatter_kernel<<<nbuck, 256, 0, stream>>>(binned, bucket_off, bucket_cnt,
                                                    row_ptr, src_sorted, N);

    for (int l = 0; l < 3; l++) {
        const float* b    = (const float*)d_in[7 + 6 * l];
        const float* hin = (l == 0) ? nw : hbuf;
        float* hout = (l == 2) ? (float*)d_out : hbuf;
        float* stats_prev = (l == 0) ? stats : stats + (l - 1) * 128;
        float* stats_cur  = stats + l * 128;

        gemm64_mfma_kernel<<<(ntiles + 3) / 4, 256, 0, stream>>>(
            hin, wfrag + l * 8192,
            wlr + l * 128, wlr + l * 128 + 64,
            stats_prev,
            (l == 0) ? (const float*)d_in[8] : (const float*)d_in[8 + 6 * (l - 1)],
            (l == 0) ? (const float*)d_in[9] : (const float*)d_in[9 + 6 * (l - 1)],
            (l > 0) ? 1 : 0, invN,
            feat, el, er, N);
        attn_agg_kernel<<<nblk_attn, 256, 0, stream>>>(row_ptr, src_sorted, el, er,
                                                       feat, b, hout, partial, N);
        bn_reduce_kernel<<<64, 128, 0, stream>>>(partial, stats_cur, nblk_attn);
    }
    // final BatchNorm (no ELU) on d_out
    bn_apply_kernel<<<2048, 256, 0, stream>>>((float*)d_out, stats + 2 * 128,
                                              (const float*)d_in[8 + 12],
                                              (const float*)d_in[9 + 12],
                                              N, 0);
}

// Round 11
// 463.033 us; speedup vs baseline: 1.6631x; 1.0436x over previous
//
#include <hip/hip_runtime.h>
#include <hip/hip_bf16.h>
#include <math.h>

#define DIM 64
#define BSHIFT 9
#define BNODES 512   // 1 << BSHIFT
#define MAXB 256     // max coarse buckets (N <= 131072)
#define EPT 8
#define CHUNK 2048   // EPT * 256

typedef __attribute__((ext_vector_type(8))) short bf16x8;
typedef __attribute__((ext_vector_type(4))) float f32x4;

__device__ __forceinline__ short f2bf(float x) {
    union { __hip_bfloat16 b; short s; } u;
    u.b = __float2bfloat16(x);
    return u.s;
}
__device__ __forceinline__ float bf2f(short s) {
    return __uint_as_float(((unsigned)(unsigned short)s) << 16);
}

// ---------------- CSR build: binned sort, merged tail (r11) ----------------
// r8 lesson: scatter needs WRITE LOCALITY (direct-atomic scatter dirtied 64B
// lines randomly across 8 XCDs -> 107MB writeback). The binned design keeps
// writes in per-bucket ~32KB slices. r11: node_count+scan1/2/3+final_scatter
// merged into ONE per-bucket kernel (row_ptr = bucket_off[b] + local excl,
// globally correct since bucket_off is the global cumsum).

__global__ void bin_count_kernel(const int* __restrict__ dst, int* __restrict__ bucket_cnt, int E) {
    __shared__ int h[MAXB];
    int t = threadIdx.x;
    h[t] = 0;
    __syncthreads();
    for (int i = blockIdx.x * blockDim.x + t; i < E; i += gridDim.x * blockDim.x)
        atomicAdd(&h[dst[i] >> BSHIFT], 1);
    __syncthreads();
    if (h[t]) atomicAdd(&bucket_cnt[t], h[t]);
}

__global__ void bucket_scan_kernel(const int* __restrict__ bucket_cnt,
                                   int* __restrict__ bucket_off, int* __restrict__ bucket_fill) {
    __shared__ int s[MAXB];
    int t = threadIdx.x;
    int v = bucket_cnt[t];
    s[t] = v;
    __syncthreads();
    for (int off = 1; off < MAXB; off <<= 1) {
        int x = (t >= off) ? s[t - off] : 0;
        __syncthreads();
        s[t] += x;
        __syncthreads();
    }
    bucket_off[t] = s[t] - v;
    bucket_fill[t] = 0;
}

__global__ __launch_bounds__(256) void bin_scatter_kernel(
    const int* __restrict__ src, const int* __restrict__ dst,
    const int* __restrict__ bucket_off, int* __restrict__ bucket_fill,
    unsigned long long* __restrict__ binned, int E) {
    __shared__ int lcnt[MAXB];
    __shared__ int lbase[MAXB];
    int t = threadIdx.x;
    lcnt[t] = 0;
    __syncthreads();
    int base = blockIdx.x * CHUNK;
    unsigned long long pair[EPT];
    int slot[EPT];
#pragma unroll
    for (int j = 0; j < EPT; j++) {
        int idx = base + j * 256 + t;
        if (idx < E) {
            int s = src[idx], d = dst[idx];
            pair[j] = ((unsigned long long)(unsigned)d << 32) | (unsigned)s;
            slot[j] = atomicAdd(&lcnt[d >> BSHIFT], 1);
        } else {
            slot[j] = -1;
        }
    }
    __syncthreads();
    int c = lcnt[t];
    if (c) lbase[t] = atomicAdd(&bucket_fill[t], c);
    __syncthreads();
#pragma unroll
    for (int j = 0; j < EPT; j++) {
        if (slot[j] >= 0) {
            int b = (int)(pair[j] >> 32) >> BSHIFT;
            binned[(size_t)bucket_off[b] + lbase[b] + slot[j]] = pair[j];
        }
    }
}

// One block per bucket: count 512 node degrees in LDS, local exclusive scan,
// write row_ptr (global = bucket_off[b] + excl), scatter src into the
// bucket's contiguous src_sorted slice (~32KB window -> write locality).
__global__ __launch_bounds__(256) void csr_finalize_kernel(
    const unsigned long long* __restrict__ binned, const int* __restrict__ bucket_off,
    const int* __restrict__ bucket_cnt, int* __restrict__ row_ptr,
    int* __restrict__ src_sorted, int N, int E, int nbuck) {
    __shared__ int cnt[BNODES];
    __shared__ int excl[BNODES];
    __shared__ int ps[256];
    int b = blockIdx.x, t = threadIdx.x;
    for (int i = t; i < BNODES; i += 256) cnt[i] = 0;
    __syncthreads();
    int s0 = bucket_off[b], c = bucket_cnt[b];
    for (int i = t; i < c; i += 256)
        atomicAdd(&cnt[(int)(binned[(size_t)s0 + i] >> 32) & (BNODES - 1)], 1);
    __syncthreads();
    // exclusive scan over 512 via pairs (256 threads)
    int a0 = cnt[2 * t], a1 = cnt[2 * t + 1];
    int pairsum = a0 + a1;
    ps[t] = pairsum;
    __syncthreads();
    for (int off = 1; off < 256; off <<= 1) {
        int x = (t >= off) ? ps[t - off] : 0;
        __syncthreads();
        ps[t] += x;
        __syncthreads();
    }
    int run = ps[t] - pairsum;          // exclusive pair prefix
    excl[2 * t] = run;
    excl[2 * t + 1] = run + a0;
    __syncthreads();
    int nbase = b << BSHIFT;
    for (int i = t; i < BNODES; i += 256)
        if (nbase + i < N) row_ptr[nbase + i] = s0 + excl[i];
    if (b == nbuck - 1 && t == 0) row_ptr[N] = E;
    // reuse cnt as fill
    for (int i = t; i < BNODES; i += 256) cnt[i] = 0;
    __syncthreads();
    for (int i = t; i < c; i += 256) {
        unsigned long long p = binned[(size_t)s0 + i];
        int d = (int)(p >> 32) & (BNODES - 1);
        int pos = excl[d] + atomicAdd(&cnt[d], 1);
        src_sorted[(size_t)s0 + pos] = (int)(p & 0xffffffffu);
    }
}

// ---------------- per-layer kernels ----------------

// Per-layer prep (runs once, 3 blocks): wl/wr = (W@al/ar)*log2e, plus
// pre-packed hi/lo split-bf16 W fragments in the gemm wave's layout.
__global__ void wlr_kernel(
    const float* __restrict__ W1, const float* __restrict__ al1, const float* __restrict__ ar1,
    const float* __restrict__ W2, const float* __restrict__ al2, const float* __restrict__ ar2,
    const float* __restrict__ W3, const float* __restrict__ al3, const float* __restrict__ ar3,
    float* __restrict__ wlr, short* __restrict__ wfrag) {
    const float* W  = (blockIdx.x == 0) ? W1  : (blockIdx.x == 1) ? W2  : W3;
    const float* al = (blockIdx.x == 0) ? al1 : (blockIdx.x == 1) ? al2 : al3;
    const float* ar = (blockIdx.x == 0) ? ar1 : (blockIdx.x == 1) ? ar2 : ar3;
    int t = threadIdx.x;
    short* whi = wfrag + blockIdx.x * 8192;
    short* wlo = whi + 4096;
    for (int idx = t; idx < 4096; idx += 256) {
        int j = idx & 7, li = (idx >> 3) & 15, quad = (idx >> 7) & 3;
        int nt = (idx >> 9) & 3, ks = idx >> 11;
        int k = ks * 32 + quad * 8 + j, nn = nt * 16 + li;
        float w = W[k * 64 + nn];
        short hi = f2bf(w);
        whi[idx] = hi;
        wlo[idx] = f2bf(w - bf2f(hi));
    }
    if (t < 64) {
        float l = 0.f, r = 0.f;
        for (int nn = 0; nn < 64; nn++) {
            float w = W[t * 64 + nn];
            l = fmaf(w, al[nn], l);
            r = fmaf(w, ar[nn], r);
        }
        const float LOG2E = 1.4426950408889634f;
        wlr[blockIdx.x * 128 + t] = l * LOG2E;
        wlr[blockIdx.x * 128 + 64 + t] = r * LOG2E;
    }
}

// MFMA GEMM: feat(bf16) = bnelu(h) @ W ; el = act.wl ; er = act.wr
// r11: input h may be bf16 (intermediate layers) -> one 16B load per ks
// instead of two.
__global__ __launch_bounds__(256) void gemm64_mfma_kernel(
    const void* __restrict__ hvoid, int in_bf16, const short* __restrict__ wfrag_l,
    const float* __restrict__ wl, const float* __restrict__ wr,
    const float* __restrict__ stats, const float* __restrict__ g,
    const float* __restrict__ beta, int do_bn, float invN,
    __hip_bfloat16* __restrict__ feat, float* __restrict__ el, float* __restrict__ er,
    int n) {
    int t = threadIdx.x;
    int lane = t & 63;
    int li = lane & 15;
    int quad = lane >> 4;
    int wv = t >> 6;

    const short* whi = wfrag_l;
    const short* wlo = wfrag_l + 4096;
    bf16x8 b_hi[2][4], b_lo[2][4];
#pragma unroll
    for (int ks = 0; ks < 2; ks++)
#pragma unroll
        for (int nt = 0; nt < 4; nt++) {
            int base = (((ks * 4 + nt) * 4 + quad) * 16 + li) * 8;
            b_hi[ks][nt] = *(const bf16x8*)(whi + base);
            b_lo[ks][nt] = *(const bf16x8*)(wlo + base);
        }
    float wlv[2][8], wrv[2][8];
#pragma unroll
    for (int ks = 0; ks < 2; ks++)
#pragma unroll
        for (int j = 0; j < 8; j++) {
            wlv[ks][j] = wl[ks * 32 + quad * 8 + j];
            wrv[ks][j] = wr[ks * 32 + quad * 8 + j];
        }

    float sc[2][8], sh[2][8];
    if (do_bn) {
#pragma unroll
        for (int ks = 0; ks < 2; ks++)
#pragma unroll
            for (int j = 0; j < 8; j++) {
                int k = ks * 32 + quad * 8 + j;
                float mu = stats[k] * invN;
                float var = fmaf(-mu, mu, stats[64 + k] * invN);
                float inv = rsqrtf(var + 1e-5f) * g[k];
                sc[ks][j] = inv;
                sh[ks][j] = beta[k] - mu * inv;
            }
    }

    int ntiles = (n + 15) >> 4;
    for (int tile = blockIdx.x * 4 + wv; tile < ntiles; tile += gridDim.x * 4) {
        int m0 = tile << 4;
        int rrow = m0 + li;
        size_t rowbase = (size_t)((rrow < n) ? rrow : (n - 1)) * 64;
        bf16x8 a_hi[2], a_lo[2];
        float elp = 0.f, erp = 0.f;
#pragma unroll
        for (int ks = 0; ks < 2; ks++) {
            float x[8];
            if (in_bf16) {
                const unsigned short* rp = (const unsigned short*)hvoid + rowbase + ks * 32 + quad * 8;
                uint4 pv = *(const uint4*)rp;
                x[0] = bf2f((short)(pv.x & 0xffffu)); x[1] = bf2f((short)(pv.x >> 16));
                x[2] = bf2f((short)(pv.y & 0xffffu)); x[3] = bf2f((short)(pv.y >> 16));
                x[4] = bf2f((short)(pv.z & 0xffffu)); x[5] = bf2f((short)(pv.z >> 16));
                x[6] = bf2f((short)(pv.w & 0xffffu)); x[7] = bf2f((short)(pv.w >> 16));
            } else {
                const float* rp = (const float*)hvoid + rowbase + ks * 32 + quad * 8;
                float4 v0 = *(const float4*)rp;
                float4 v1 = *(const float4*)(rp + 4);
                x[0] = v0.x; x[1] = v0.y; x[2] = v0.z; x[3] = v0.w;
                x[4] = v1.x; x[5] = v1.y; x[6] = v1.z; x[7] = v1.w;
            }
#pragma unroll
            for (int j = 0; j < 8; j++) {
                float v = x[j];
                if (do_bn) {
                    v = fmaf(v, sc[ks][j], sh[ks][j]);
                    if (v < 0.f) v = expm1f(v);   // ELU
                }
                elp = fmaf(v, wlv[ks][j], elp);
                erp = fmaf(v, wrv[ks][j], erp);
                short hi = f2bf(v);
                a_hi[ks][j] = hi;
                a_lo[ks][j] = f2bf(v - bf2f(hi));
            }
        }
        elp += __shfl_xor(elp, 16, 64);
        elp += __shfl_xor(elp, 32, 64);
        erp += __shfl_xor(erp, 16, 64);
        erp += __shfl_xor(erp, 32, 64);
        if (lane < 16 && m0 + li < n) {
            el[m0 + li] = elp;
            er[m0 + li] = erp;
        }
        f32x4 acc[4];
#pragma unroll
        for (int nt = 0; nt < 4; nt++) acc[nt] = (f32x4){0.f, 0.f, 0.f, 0.f};
#pragma unroll
        for (int ks = 0; ks < 2; ks++)
#pragma unroll
            for (int nt = 0; nt < 4; nt++) {
                acc[nt] = __builtin_amdgcn_mfma_f32_16x16x32_bf16(a_hi[ks], b_hi[ks][nt], acc[nt], 0, 0, 0);
                acc[nt] = __builtin_amdgcn_mfma_f32_16x16x32_bf16(a_lo[ks], b_hi[ks][nt], acc[nt], 0, 0, 0);
                acc[nt] = __builtin_amdgcn_mfma_f32_16x16x32_bf16(a_hi[ks], b_lo[ks][nt], acc[nt], 0, 0, 0);
            }
#pragma unroll
        for (int nt = 0; nt < 4; nt++)
#pragma unroll
            for (int reg = 0; reg < 4; reg++) {
                int wrow = m0 + quad * 4 + reg;
                if (wrow < n) {
                    union { __hip_bfloat16 b; short s; } u;
                    u.s = f2bf(acc[nt][reg]);
                    feat[(size_t)wrow * 64 + nt * 16 + li] = u.b;
                }
            }
    }
}

// Fused edge-score + softmax + weighted aggregate. r6 structure (proven
// fastest: 48.7us): FOUR nodes per wave, 8 edge-slots x 8 dims, 2-deep
// named ping-pong prefetch, exp2 on pre-scaled el/er, -inf masking,
// reduce-scatter epilogue. r11: output dtype flag (bf16 intermediates).
// r10 lesson: fused BN-stats epilogue cost more than the separate
// streaming bn_stats kernel it replaced -- reverted.
#define AGG_LOAD(P, ELV, POS)                                  \
    {                                                          \
        int idx = (POS) + q;                                   \
        bool v = idx < end;                                    \
        int idc = v ? idx : end - 1;                           \
        int sn = src_sorted[idc];                              \
        float ev = el[sn];                                     \
        ELV = v ? ev : -INFINITY;                              \
        P = featv[(size_t)sn * 8 + li];                        \
    }

#define AGG_CHUNK(P, ELV)                                      \
    {                                                          \
        float e = ELV + er_n;                                  \
        e = fmaxf(e, 0.2f * e);                                \
        float w = exp2f(e);                                    \
        s += w;                                                \
        a0 = fmaf(w, __uint_as_float(P.x << 16), a0);          \
        a1 = fmaf(w, __uint_as_float(P.x & 0xffff0000u), a1);  \
        a2 = fmaf(w, __uint_as_float(P.y << 16), a2);          \
        a3 = fmaf(w, __uint_as_float(P.y & 0xffff0000u), a3);  \
        a4 = fmaf(w, __uint_as_float(P.z << 16), a4);          \
        a5 = fmaf(w, __uint_as_float(P.z & 0xffff0000u), a5);  \
        a6 = fmaf(w, __uint_as_float(P.w << 16), a6);          \
        a7 = fmaf(w, __uint_as_float(P.w & 0xffff0000u), a7);  \
    }

__global__ __launch_bounds__(256) void attn_agg_kernel(
    const int* __restrict__ row_ptr, const int* __restrict__ src_sorted,
    const float* __restrict__ el, const float* __restrict__ er,
    const __hip_bfloat16* __restrict__ feat, const float* __restrict__ bias,
    void* __restrict__ outv, int out_bf16, int n) {
    int t = threadIdx.x, lane = t & 63;
    int q = lane >> 3;        // edge slot 0..7
    int li = lane & 7;        // dim octet 0..7
    int d = li * 8 + ((q & 1) << 2) + (q & 2) + ((q >> 2) & 1);  // this lane's dim
    float bias_d = bias[d];
    int node0 = blockIdx.x * 16 + (t >> 6) * 4;   // 4 nodes per wave
    const uint4* featv = (const uint4*)feat;

#pragma unroll
    for (int j = 0; j < 4; j++) {
        int node = node0 + j;
        if (node >= n) break;                      // wave-uniform
        int start = row_ptr[node], end = row_ptr[node + 1];
        float er_n = er[node];

        float s = 0.f;
        float a0 = 0.f, a1 = 0.f, a2 = 0.f, a3 = 0.f;
        float a4 = 0.f, a5 = 0.f, a6 = 0.f, a7 = 0.f;

        uint4 pA = {0u, 0u, 0u, 0u}, pB = {0u, 0u, 0u, 0u};
        float elA = -INFINITY, elB = -INFINITY;
        if (start < end) AGG_LOAD(pA, elA, start)
        if (start + 8 < end) AGG_LOAD(pB, elB, start + 8)
        for (int i = start; i < end; i += 16) {    // all branches wave-uniform
            AGG_CHUNK(pA, elA)
            if (i + 16 < end) AGG_LOAD(pA, elA, i + 16)
            if (i + 8 < end) {
                AGG_CHUNK(pB, elB)
                if (i + 24 < end) AGG_LOAD(pB, elB, i + 24)
            }
        }
        s += __shfl_xor(s, 8, 64);
        s += __shfl_xor(s, 16, 64);
        s += __shfl_xor(s, 32, 64);
        bool b0 = (q & 1) != 0;
        float t0 = __shfl_xor(a0, 8, 64), t1 = __shfl_xor(a1, 8, 64);
        float t2 = __shfl_xor(a2, 8, 64), t3 = __shfl_xor(a3, 8, 64);
        float t4 = __shfl_xor(a4, 8, 64), t5 = __shfl_xor(a5, 8, 64);
        float t6 = __shfl_xor(a6, 8, 64), t7 = __shfl_xor(a7, 8, 64);
        float x0 = b0 ? (a4 + t4) : (a0 + t0);
        float x1 = b0 ? (a5 + t5) : (a1 + t1);
        float y0 = b0 ? (a6 + t6) : (a2 + t2);
        float y1 = b0 ? (a7 + t7) : (a3 + t3);
        bool b1 = (q & 2) != 0;
        float u0 = __shfl_xor(x0, 16, 64), u1 = __shfl_xor(x1, 16, 64);
        float v0 = __shfl_xor(y0, 16, 64), v1 = __shfl_xor(y1, 16, 64);
        float z0 = b1 ? (y0 + v0) : (x0 + u0);
        float z1 = b1 ? (y1 + v1) : (x1 + u1);
        z0 += __shfl_xor(z0, 32, 64);
        z1 += __shfl_xor(z1, 32, 64);
        float val = ((q & 4) != 0) ? z1 : z0;
        float inv_s = (s > 0.f) ? 1.f / s : 0.f;
        float x = fmaf(val, inv_s, bias_d);
        if (out_bf16) {
            union { __hip_bfloat16 b; short s2; } u;
            u.s2 = f2bf(x);
            ((__hip_bfloat16*)outv)[(size_t)node * 64 + d] = u.b;
        } else {
            ((float*)outv)[(size_t)node * 64 + d] = x;
        }
    }
}

// column sums / sumsq (input may be bf16)
__global__ __launch_bounds__(256) void bn_stats_kernel(const void* __restrict__ hvoid,
                                                       int in_bf16,
                                                       float* __restrict__ stats, int n) {
    __shared__ float ls[256], lss[256];
    int t = threadIdx.x, lane = t & 63;
    int w = blockIdx.x * 4 + (t >> 6);
    int stride = gridDim.x * 4;
    float s = 0.f, ss = 0.f;
    for (int row = w; row < n; row += stride) {
        float v;
        if (in_bf16) v = bf2f((short)((const unsigned short*)hvoid)[(size_t)row * DIM + lane]);
        else         v = ((const float*)hvoid)[(size_t)row * DIM + lane];
        s += v;
        ss = fmaf(v, v, ss);
    }
    ls[t] = s; lss[t] = ss;
    __syncthreads();
    if (t < 64) {
        float a = ls[t] + ls[t + 64] + ls[t + 128] + ls[t + 192];
        float b = lss[t] + lss[t + 64] + lss[t + 128] + lss[t + 192];
        atomicAdd(&stats[t], a);
        atomicAdd(&stats[64 + t], b);
    }
}

__global__ void bn_apply_kernel(float* __restrict__ h, const float* __restrict__ stats,
                                const float* __restrict__ g, const float* __restrict__ beta,
                                int n, int do_elu) {
    int i = blockIdx.x * blockDim.x + threadIdx.x;
    int total = n * DIM;
    int stride = gridDim.x * blockDim.x;
    float invN = 1.f / (float)n;
    for (; i < total; i += stride) {
        int c = i & 63;
        float mu = stats[c] * invN;
        float var = fmaf(-mu, mu, stats[DIM + c] * invN);
        float x = (h[i] - mu) * rsqrtf(var + 1e-5f) * g[c] + beta[c];
        if (do_elu && x < 0.f) x = expm1f(x);
        h[i] = x;
    }
}

// ---------------- launch ----------------

extern "C" void kernel_launch(void* const* d_in, const int* in_sizes, int n_in,
                              void* d_out, int out_size, void* d_ws, size_t ws_size,
                              hipStream_t stream) {
    const float* nw = (const float*)d_in[0];
    const int* src = (const int*)d_in[2];
    const int* dst = (const int*)d_in[3];
    const int N = in_sizes[0] / DIM;
    const int E = in_sizes[2];
    const float invN = 1.f / (float)N;
    const int nbuck = (N + BNODES - 1) >> BSHIFT;

    char* ws = (char*)d_ws;
    size_t off = 0;
    auto alloc = [&](size_t bytes) -> void* {
        void* p = ws + off;
        off += (bytes + 255) & ~(size_t)255;
        return p;
    };
    int* row_ptr      = (int*)alloc(((size_t)N + 1) * 4);
    int* bucket_cnt   = (int*)alloc(MAXB * 4);
    int* bucket_off   = (int*)alloc(MAXB * 4);
    int* bucket_fill  = (int*)alloc(MAXB * 4);
    unsigned long long* binned = (unsigned long long*)alloc((size_t)E * 8);
    int* src_sorted   = (int*)alloc((size_t)E * 4);
    float* el         = (float*)alloc((size_t)N * 4);
    float* er         = (float*)alloc((size_t)N * 4);
    __hip_bfloat16* feat = (__hip_bfloat16*)alloc((size_t)N * DIM * 2);
    __hip_bfloat16* hbuf = (__hip_bfloat16*)alloc((size_t)N * DIM * 2);  // bf16 intermediates
    float* stats      = (float*)alloc(3 * 512);     // 3 layer slots of 128 floats
    float* wlr        = (float*)alloc(3 * 128 * 4);
    short* wfrag      = (short*)alloc(3 * 8192 * 2); // [layer][hi/lo][4096] bf16

    int ntiles = (N + 15) >> 4;

    // CSR build (binned, once) + per-layer W prep
    hipMemsetAsync(bucket_cnt, 0, MAXB * 4, stream);
    hipMemsetAsync(stats, 0, 3 * 512, stream);
    wlr_kernel<<<3, 256, 0, stream>>>(
        (const float*)d_in[4],  (const float*)d_in[5],  (const float*)d_in[6],
        (const float*)d_in[10], (const float*)d_in[11], (const float*)d_in[12],
        (const float*)d_in[16], (const float*)d_in[17], (const float*)d_in[18],
        wlr, wfrag);
    bin_count_kernel<<<256, 256, 0, stream>>>(dst, bucket_cnt, E);
    bucket_scan_kernel<<<1, MAXB, 0, stream>>>(bucket_cnt, bucket_off, bucket_fill);
    bin_scatter_kernel<<<(E + CHUNK - 1) / CHUNK, 256, 0, stream>>>(
        src, dst, bucket_off, bucket_fill, binned, E);
    csr_finalize_kernel<<<nbuck, 256, 0, stream>>>(binned, bucket_off, bucket_cnt,
                                                   row_ptr, src_sorted, N, E, nbuck);

    for (int l = 0; l < 3; l++) {
        const float* b    = (const float*)d_in[7 + 6 * l];
        const void* hin   = (l == 0) ? (const void*)nw : (const void*)hbuf;
        int in_bf16       = (l == 0) ? 0 : 1;
        void* hout        = (l == 2) ? (void*)d_out : (void*)hbuf;
        int out_bf16      = (l == 2) ? 0 : 1;
        float* stats_prev = (l == 0) ? stats : stats + (l - 1) * 128;
        float* stats_cur  = stats + l * 128;

        gemm64_mfma_kernel<<<(ntiles + 3) / 4, 256, 0, stream>>>(
            hin, in_bf16, wfrag + l * 8192,
            wlr + l * 128, wlr + l * 128 + 64,
            stats_prev,
            (l == 0) ? (const float*)d_in[8] : (const float*)d_in[8 + 6 * (l - 1)],
            (l == 0) ? (const float*)d_in[9] : (const float*)d_in[9 + 6 * (l - 1)],
            (l > 0) ? 1 : 0, invN,
            feat, el, er, N);
        attn_agg_kernel<<<(N + 15) / 16, 256, 0, stream>>>(row_ptr, src_sorted, el, er,
                                                           feat, b, hout, out_bf16, N);
        bn_stats_kernel<<<512, 256, 0, stream>>>(hout, out_bf16, stats_cur, N);
    }
    // final BatchNorm (no ELU) on d_out
    bn_apply_kernel<<<2048, 256, 0, stream>>>((float*)d_out, stats + 2 * 128,
                                              (const float*)d_in[8 + 12],
                                              (const float*)d_in[9 + 12],
                                              N, 0);
}

// Round 12
// 446.305 us; speedup vs baseline: 1.7255x; 1.0375x over previous
//
#include <hip/hip_runtime.h>
#include <hip/hip_bf16.h>
#include <math.h>

#define DIM 64
#define BSHIFT 9
#define BNODES 512   // 1 << BSHIFT
#define MAXB 256     // max coarse buckets (N <= 131072)
#define EPT 8
#define CHUNK 2048   // EPT * 256

typedef __attribute__((ext_vector_type(8))) short bf16x8;
typedef __attribute__((ext_vector_type(4))) float f32x4;

__device__ __forceinline__ short f2bf(float x) {
    union { __hip_bfloat16 b; short s; } u;
    u.b = __float2bfloat16(x);
    return u.s;
}
__device__ __forceinline__ float bf2f(short s) {
    return __uint_as_float(((unsigned)(unsigned short)s) << 16);
}

// ---------------- CSR build: binned sort, merged tail ----------------
// r8 lesson: scatter needs WRITE LOCALITY (direct-atomic scatter dirtied 64B
// lines randomly across 8 XCDs -> 107MB writeback). The binned design keeps
// writes in per-bucket ~32KB slices. r11: node_count+scan1/2/3+final_scatter
// merged into ONE per-bucket kernel.

__global__ void bin_count_kernel(const int* __restrict__ dst, int* __restrict__ bucket_cnt, int E) {
    __shared__ int h[MAXB];
    int t = threadIdx.x;
    h[t] = 0;
    __syncthreads();
    for (int i = blockIdx.x * blockDim.x + t; i < E; i += gridDim.x * blockDim.x)
        atomicAdd(&h[dst[i] >> BSHIFT], 1);
    __syncthreads();
    if (h[t]) atomicAdd(&bucket_cnt[t], h[t]);
}

__global__ void bucket_scan_kernel(const int* __restrict__ bucket_cnt,
                                   int* __restrict__ bucket_off, int* __restrict__ bucket_fill) {
    __shared__ int s[MAXB];
    int t = threadIdx.x;
    int v = bucket_cnt[t];
    s[t] = v;
    __syncthreads();
    for (int off = 1; off < MAXB; off <<= 1) {
        int x = (t >= off) ? s[t - off] : 0;
        __syncthreads();
        s[t] += x;
        __syncthreads();
    }
    bucket_off[t] = s[t] - v;
    bucket_fill[t] = 0;
}

__global__ __launch_bounds__(256) void bin_scatter_kernel(
    const int* __restrict__ src, const int* __restrict__ dst,
    const int* __restrict__ bucket_off, int* __restrict__ bucket_fill,
    unsigned long long* __restrict__ binned, int E) {
    __shared__ int lcnt[MAXB];
    __shared__ int lbase[MAXB];
    int t = threadIdx.x;
    lcnt[t] = 0;
    __syncthreads();
    int base = blockIdx.x * CHUNK;
    unsigned long long pair[EPT];
    int slot[EPT];
#pragma unroll
    for (int j = 0; j < EPT; j++) {
        int idx = base + j * 256 + t;
        if (idx < E) {
            int s = src[idx], d = dst[idx];
            pair[j] = ((unsigned long long)(unsigned)d << 32) | (unsigned)s;
            slot[j] = atomicAdd(&lcnt[d >> BSHIFT], 1);
        } else {
            slot[j] = -1;
        }
    }
    __syncthreads();
    int c = lcnt[t];
    if (c) lbase[t] = atomicAdd(&bucket_fill[t], c);
    __syncthreads();
#pragma unroll
    for (int j = 0; j < EPT; j++) {
        if (slot[j] >= 0) {
            int b = (int)(pair[j] >> 32) >> BSHIFT;
            binned[(size_t)bucket_off[b] + lbase[b] + slot[j]] = pair[j];
        }
    }
}

// One block per bucket: count 512 node degrees in LDS, local exclusive scan,
// write row_ptr (global = bucket_off[b] + excl), scatter src into the
// bucket's contiguous src_sorted slice (~32KB window -> write locality).
__global__ __launch_bounds__(256) void csr_finalize_kernel(
    const unsigned long long* __restrict__ binned, const int* __restrict__ bucket_off,
    const int* __restrict__ bucket_cnt, int* __restrict__ row_ptr,
    int* __restrict__ src_sorted, int N, int E, int nbuck) {
    __shared__ int cnt[BNODES];
    __shared__ int excl[BNODES];
    __shared__ int ps[256];
    int b = blockIdx.x, t = threadIdx.x;
    for (int i = t; i < BNODES; i += 256) cnt[i] = 0;
    __syncthreads();
    int s0 = bucket_off[b], c = bucket_cnt[b];
    for (int i = t; i < c; i += 256)
        atomicAdd(&cnt[(int)(binned[(size_t)s0 + i] >> 32) & (BNODES - 1)], 1);
    __syncthreads();
    // exclusive scan over 512 via pairs (256 threads)
    int a0 = cnt[2 * t], a1 = cnt[2 * t + 1];
    int pairsum = a0 + a1;
    ps[t] = pairsum;
    __syncthreads();
    for (int off = 1; off < 256; off <<= 1) {
        int x = (t >= off) ? ps[t - off] : 0;
        __syncthreads();
        ps[t] += x;
        __syncthreads();
    }
    int run = ps[t] - pairsum;          // exclusive pair prefix
    excl[2 * t] = run;
    excl[2 * t + 1] = run + a0;
    __syncthreads();
    int nbase = b << BSHIFT;
    for (int i = t; i < BNODES; i += 256)
        if (nbase + i < N) row_ptr[nbase + i] = s0 + excl[i];
    if (b == nbuck - 1 && t == 0) row_ptr[N] = E;
    // reuse cnt as fill
    for (int i = t; i < BNODES; i += 256) cnt[i] = 0;
    __syncthreads();
    for (int i = t; i < c; i += 256) {
        unsigned long long p = binned[(size_t)s0 + i];
        int d = (int)(p >> 32) & (BNODES - 1);
        int pos = excl[d] + atomicAdd(&cnt[d], 1);
        src_sorted[(size_t)s0 + pos] = (int)(p & 0xffffffffu);
    }
}

// ---------------- per-layer kernels ----------------

// Per-layer prep (runs once, 3 blocks): wl/wr = (W@al/ar)*log2e, plus
// pre-packed hi/lo split-bf16 W fragments in the gemm wave's layout.
// r12: also zeros bucket_cnt (block 0) and stats (block 1) -- folds the two
// hipMemsetAsync dispatches into this launch (stream-ordered before use).
__global__ void wlr_kernel(
    const float* __restrict__ W1, const float* __restrict__ al1, const float* __restrict__ ar1,
    const float* __restrict__ W2, const float* __restrict__ al2, const float* __restrict__ ar2,
    const float* __restrict__ W3, const float* __restrict__ al3, const float* __restrict__ ar3,
    float* __restrict__ wlr, short* __restrict__ wfrag,
    int* __restrict__ bucket_cnt, float* __restrict__ stats) {
    const float* W  = (blockIdx.x == 0) ? W1  : (blockIdx.x == 1) ? W2  : W3;
    const float* al = (blockIdx.x == 0) ? al1 : (blockIdx.x == 1) ? al2 : al3;
    const float* ar = (blockIdx.x == 0) ? ar1 : (blockIdx.x == 1) ? ar2 : ar3;
    int t = threadIdx.x;
    if (blockIdx.x == 0) bucket_cnt[t] = 0;                 // MAXB = 256
    if (blockIdx.x == 1) { stats[t] = 0.f; if (t < 128) stats[256 + t] = 0.f; }  // 384 floats
    short* whi = wfrag + blockIdx.x * 8192;
    short* wlo = whi + 4096;
    for (int idx = t; idx < 4096; idx += 256) {
        int j = idx & 7, li = (idx >> 3) & 15, quad = (idx >> 7) & 3;
        int nt = (idx >> 9) & 3, ks = idx >> 11;
        int k = ks * 32 + quad * 8 + j, nn = nt * 16 + li;
        float w = W[k * 64 + nn];
        short hi = f2bf(w);
        whi[idx] = hi;
        wlo[idx] = f2bf(w - bf2f(hi));
    }
    if (t < 64) {
        float l = 0.f, r = 0.f;
        for (int nn = 0; nn < 64; nn++) {
            float w = W[t * 64 + nn];
            l = fmaf(w, al[nn], l);
            r = fmaf(w, ar[nn], r);
        }
        const float LOG2E = 1.4426950408889634f;
        wlr[blockIdx.x * 128 + t] = l * LOG2E;
        wlr[blockIdx.x * 128 + 64 + t] = r * LOG2E;
    }
}

// MFMA GEMM: feat(bf16) = bnelu(h) @ W ; el = act.wl ; er = act.wr
// Input h may be bf16 (intermediate layers). r12: launched at ntiles/16
// blocks -> each wave loops ~4 tiles, amortizing the prologue 4x.
__global__ __launch_bounds__(256) void gemm64_mfma_kernel(
    const void* __restrict__ hvoid, int in_bf16, const short* __restrict__ wfrag_l,
    const float* __restrict__ wl, const float* __restrict__ wr,
    const float* __restrict__ stats, const float* __restrict__ g,
    const float* __restrict__ beta, int do_bn, float invN,
    __hip_bfloat16* __restrict__ feat, float* __restrict__ el, float* __restrict__ er,
    int n) {
    int t = threadIdx.x;
    int lane = t & 63;
    int li = lane & 15;
    int quad = lane >> 4;
    int wv = t >> 6;

    const short* whi = wfrag_l;
    const short* wlo = wfrag_l + 4096;
    bf16x8 b_hi[2][4], b_lo[2][4];
#pragma unroll
    for (int ks = 0; ks < 2; ks++)
#pragma unroll
        for (int nt = 0; nt < 4; nt++) {
            int base = (((ks * 4 + nt) * 4 + quad) * 16 + li) * 8;
            b_hi[ks][nt] = *(const bf16x8*)(whi + base);
            b_lo[ks][nt] = *(const bf16x8*)(wlo + base);
        }
    float wlv[2][8], wrv[2][8];
#pragma unroll
    for (int ks = 0; ks < 2; ks++)
#pragma unroll
        for (int j = 0; j < 8; j++) {
            wlv[ks][j] = wl[ks * 32 + quad * 8 + j];
            wrv[ks][j] = wr[ks * 32 + quad * 8 + j];
        }

    float sc[2][8], sh[2][8];
    if (do_bn) {
#pragma unroll
        for (int ks = 0; ks < 2; ks++)
#pragma unroll
            for (int j = 0; j < 8; j++) {
                int k = ks * 32 + quad * 8 + j;
                float mu = stats[k] * invN;
                float var = fmaf(-mu, mu, stats[64 + k] * invN);
                float inv = rsqrtf(var + 1e-5f) * g[k];
                sc[ks][j] = inv;
                sh[ks][j] = beta[k] - mu * inv;
            }
    }

    int ntiles = (n + 15) >> 4;
    for (int tile = blockIdx.x * 4 + wv; tile < ntiles; tile += gridDim.x * 4) {
        int m0 = tile << 4;
        int rrow = m0 + li;
        size_t rowbase = (size_t)((rrow < n) ? rrow : (n - 1)) * 64;
        bf16x8 a_hi[2], a_lo[2];
        float elp = 0.f, erp = 0.f;
#pragma unroll
        for (int ks = 0; ks < 2; ks++) {
            float x[8];
            if (in_bf16) {
                const unsigned short* rp = (const unsigned short*)hvoid + rowbase + ks * 32 + quad * 8;
                uint4 pv = *(const uint4*)rp;
                x[0] = bf2f((short)(pv.x & 0xffffu)); x[1] = bf2f((short)(pv.x >> 16));
                x[2] = bf2f((short)(pv.y & 0xffffu)); x[3] = bf2f((short)(pv.y >> 16));
                x[4] = bf2f((short)(pv.z & 0xffffu)); x[5] = bf2f((short)(pv.z >> 16));
                x[6] = bf2f((short)(pv.w & 0xffffu)); x[7] = bf2f((short)(pv.w >> 16));
            } else {
                const float* rp = (const float*)hvoid + rowbase + ks * 32 + quad * 8;
                float4 v0 = *(const float4*)rp;
                float4 v1 = *(const float4*)(rp + 4);
                x[0] = v0.x; x[1] = v0.y; x[2] = v0.z; x[3] = v0.w;
                x[4] = v1.x; x[5] = v1.y; x[6] = v1.z; x[7] = v1.w;
            }
#pragma unroll
            for (int j = 0; j < 8; j++) {
                float v = x[j];
                if (do_bn) {
                    v = fmaf(v, sc[ks][j], sh[ks][j]);
                    if (v < 0.f) v = expm1f(v);   // ELU
                }
                elp = fmaf(v, wlv[ks][j], elp);
                erp = fmaf(v, wrv[ks][j], erp);
                short hi = f2bf(v);
                a_hi[ks][j] = hi;
                a_lo[ks][j] = f2bf(v - bf2f(hi));
            }
        }
        elp += __shfl_xor(elp, 16, 64);
        elp += __shfl_xor(elp, 32, 64);
        erp += __shfl_xor(erp, 16, 64);
        erp += __shfl_xor(erp, 32, 64);
        if (lane < 16 && m0 + li < n) {
            el[m0 + li] = elp;
            er[m0 + li] = erp;
        }
        f32x4 acc[4];
#pragma unroll
        for (int nt = 0; nt < 4; nt++) acc[nt] = (f32x4){0.f, 0.f, 0.f, 0.f};
#pragma unroll
        for (int ks = 0; ks < 2; ks++)
#pragma unroll
            for (int nt = 0; nt < 4; nt++) {
                acc[nt] = __builtin_amdgcn_mfma_f32_16x16x32_bf16(a_hi[ks], b_hi[ks][nt], acc[nt], 0, 0, 0);
                acc[nt] = __builtin_amdgcn_mfma_f32_16x16x32_bf16(a_lo[ks], b_hi[ks][nt], acc[nt], 0, 0, 0);
                acc[nt] = __builtin_amdgcn_mfma_f32_16x16x32_bf16(a_hi[ks], b_lo[ks][nt], acc[nt], 0, 0, 0);
            }
#pragma unroll
        for (int nt = 0; nt < 4; nt++)
#pragma unroll
            for (int reg = 0; reg < 4; reg++) {
                int wrow = m0 + quad * 4 + reg;
                if (wrow < n) {
                    union { __hip_bfloat16 b; short s; } u;
                    u.s = f2bf(acc[nt][reg]);
                    feat[(size_t)wrow * 64 + nt * 16 + li] = u.b;
                }
            }
    }
}

// Fused edge-score + softmax + weighted aggregate. r6 structure (proven
// fastest): FOUR nodes per wave, 8 edge-slots x 8 dims, 2-deep named
// ping-pong prefetch, exp2 on pre-scaled el/er, -inf masking, reduce-scatter
// epilogue. r12: PERSISTENT waves -- 2048 co-resident blocks grid-stride
// over the node space (~3 sweeps), so the per-wave dependent-chain ramp
// (row_ptr -> src_sorted -> gathers) is paid once per wave instead of once
// per wave-generation (6250 blocks = 3 generations at 8 waves/SIMD).
#define AGG_LOAD(P, ELV, POS)                                  \
    {                                                          \
        int idx = (POS) + q;                                   \
        bool v = idx < end;                                    \
        int idc = v ? idx : end - 1;                           \
        int sn = src_sorted[idc];                              \
        float ev = el[sn];                                     \
        ELV = v ? ev : -INFINITY;                              \
        P = featv[(size_t)sn * 8 + li];                        \
    }

#define AGG_CHUNK(P, ELV)                                      \
    {                                                          \
        float e = ELV + er_n;                                  \
        e = fmaxf(e, 0.2f * e);                                \
        float w = exp2f(e);                                    \
        s += w;                                                \
        a0 = fmaf(w, __uint_as_float(P.x << 16), a0);          \
        a1 = fmaf(w, __uint_as_float(P.x & 0xffff0000u), a1);  \
        a2 = fmaf(w, __uint_as_float(P.y << 16), a2);          \
        a3 = fmaf(w, __uint_as_float(P.y & 0xffff0000u), a3);  \
        a4 = fmaf(w, __uint_as_float(P.z << 16), a4);          \
        a5 = fmaf(w, __uint_as_float(P.z & 0xffff0000u), a5);  \
        a6 = fmaf(w, __uint_as_float(P.w << 16), a6);          \
        a7 = fmaf(w, __uint_as_float(P.w & 0xffff0000u), a7);  \
    }

__global__ __launch_bounds__(256) void attn_agg_kernel(
    const int* __restrict__ row_ptr, const int* __restrict__ src_sorted,
    const float* __restrict__ el, const float* __restrict__ er,
    const __hip_bfloat16* __restrict__ feat, const float* __restrict__ bias,
    void* __restrict__ outv, int out_bf16, int n) {
    int t = threadIdx.x, lane = t & 63;
    int q = lane >> 3;        // edge slot 0..7
    int li = lane & 7;        // dim octet 0..7
    int d = li * 8 + ((q & 1) << 2) + (q & 2) + ((q >> 2) & 1);  // this lane's dim
    float bias_d = bias[d];
    const uint4* featv = (const uint4*)feat;

    for (int base = blockIdx.x * 16; base < n; base += gridDim.x * 16) {
        int node0 = base + (t >> 6) * 4;   // 4 nodes per wave per sweep
#pragma unroll
        for (int j = 0; j < 4; j++) {
            int node = node0 + j;
            if (node >= n) break;                      // wave-uniform
            int start = row_ptr[node], end = row_ptr[node + 1];
            float er_n = er[node];

            float s = 0.f;
            float a0 = 0.f, a1 = 0.f, a2 = 0.f, a3 = 0.f;
            float a4 = 0.f, a5 = 0.f, a6 = 0.f, a7 = 0.f;

            uint4 pA = {0u, 0u, 0u, 0u}, pB = {0u, 0u, 0u, 0u};
            float elA = -INFINITY, elB = -INFINITY;
            if (start < end) AGG_LOAD(pA, elA, start)
            if (start + 8 < end) AGG_LOAD(pB, elB, start + 8)
            for (int i = start; i < end; i += 16) {    // all branches wave-uniform
                AGG_CHUNK(pA, elA)
                if (i + 16 < end) AGG_LOAD(pA, elA, i + 16)
                if (i + 8 < end) {
                    AGG_CHUNK(pB, elB)
                    if (i + 24 < end) AGG_LOAD(pB, elB, i + 24)
                }
            }
            s += __shfl_xor(s, 8, 64);
            s += __shfl_xor(s, 16, 64);
            s += __shfl_xor(s, 32, 64);
            bool b0 = (q & 1) != 0;
            float t0 = __shfl_xor(a0, 8, 64), t1 = __shfl_xor(a1, 8, 64);
            float t2 = __shfl_xor(a2, 8, 64), t3 = __shfl_xor(a3, 8, 64);
            float t4 = __shfl_xor(a4, 8, 64), t5 = __shfl_xor(a5, 8, 64);
            float t6 = __shfl_xor(a6, 8, 64), t7 = __shfl_xor(a7, 8, 64);
            float x0 = b0 ? (a4 + t4) : (a0 + t0);
            float x1 = b0 ? (a5 + t5) : (a1 + t1);
            float y0 = b0 ? (a6 + t6) : (a2 + t2);
            float y1 = b0 ? (a7 + t7) : (a3 + t3);
            bool b1 = (q & 2) != 0;
            float u0 = __shfl_xor(x0, 16, 64), u1 = __shfl_xor(x1, 16, 64);
            float v0 = __shfl_xor(y0, 16, 64), v1 = __shfl_xor(y1, 16, 64);
            float z0 = b1 ? (y0 + v0) : (x0 + u0);
            float z1 = b1 ? (y1 + v1) : (x1 + u1);
            z0 += __shfl_xor(z0, 32, 64);
            z1 += __shfl_xor(z1, 32, 64);
            float val = ((q & 4) != 0) ? z1 : z0;
            float inv_s = (s > 0.f) ? 1.f / s : 0.f;
            float x = fmaf(val, inv_s, bias_d);
            if (out_bf16) {
                union { __hip_bfloat16 b; short s2; } u;
                u.s2 = f2bf(x);
                ((__hip_bfloat16*)outv)[(size_t)node * 64 + d] = u.b;
            } else {
                ((float*)outv)[(size_t)node * 64 + d] = x;
            }
        }
    }
}

// column sums / sumsq (input may be bf16)
__global__ __launch_bounds__(256) void bn_stats_kernel(const void* __restrict__ hvoid,
                                                       int in_bf16,
                                                       float* __restrict__ stats, int n) {
    __shared__ float ls[256], lss[256];
    int t = threadIdx.x, lane = t & 63;
    int w = blockIdx.x * 4 + (t >> 6);
    int stride = gridDim.x * 4;
    float s = 0.f, ss = 0.f;
    for (int row = w; row < n; row += stride) {
        float v;
        if (in_bf16) v = bf2f((short)((const unsigned short*)hvoid)[(size_t)row * DIM + lane]);
        else         v = ((const float*)hvoid)[(size_t)row * DIM + lane];
        s += v;
        ss = fmaf(v, v, ss);
    }
    ls[t] = s; lss[t] = ss;
    __syncthreads();
    if (t < 64) {
        float a = ls[t] + ls[t + 64] + ls[t + 128] + ls[t + 192];
        float b = lss[t] + lss[t + 64] + lss[t + 128] + lss[t + 192];
        atomicAdd(&stats[t], a);
        atomicAdd(&stats[64 + t], b);
    }
}

__global__ void bn_apply_kernel(float* __restrict__ h, const float* __restrict__ stats,
                                const float* __restrict__ g, const float* __restrict__ beta,
                                int n, int do_elu) {
    int i = blockIdx.x * blockDim.x + threadIdx.x;
    int total = n * DIM;
    int stride = gridDim.x * blockDim.x;
    float invN = 1.f / (float)n;
    for (; i < total; i += stride) {
        int c = i & 63;
        float mu = stats[c] * invN;
        float var = fmaf(-mu, mu, stats[DIM + c] * invN);
        float x = (h[i] - mu) * rsqrtf(var + 1e-5f) * g[c] + beta[c];
        if (do_elu && x < 0.f) x = expm1f(x);
        h[i] = x;
    }
}

// ---------------- launch ----------------

extern "C" void kernel_launch(void* const* d_in, const int* in_sizes, int n_in,
                              void* d_out, int out_size, void* d_ws, size_t ws_size,
                              hipStream_t stream) {
    const float* nw = (const float*)d_in[0];
    const int* src = (const int*)d_in[2];
    const int* dst = (const int*)d_in[3];
    const int N = in_sizes[0] / DIM;
    const int E = in_sizes[2];
    const float invN = 1.f / (float)N;
    const int nbuck = (N + BNODES - 1) >> BSHIFT;

    char* ws = (char*)d_ws;
    size_t off = 0;
    auto alloc = [&](size_t bytes) -> void* {
        void* p = ws + off;
        off += (bytes + 255) & ~(size_t)255;
        return p;
    };
    int* row_ptr      = (int*)alloc(((size_t)N + 1) * 4);
    int* bucket_cnt   = (int*)alloc(MAXB * 4);
    int* bucket_off   = (int*)alloc(MAXB * 4);
    int* bucket_fill  = (int*)alloc(MAXB * 4);
    unsigned long long* binned = (unsigned long long*)alloc((size_t)E * 8);
    int* src_sorted   = (int*)alloc((size_t)E * 4);
    float* el         = (float*)alloc((size_t)N * 4);
    float* er         = (float*)alloc((size_t)N * 4);
    __hip_bfloat16* feat = (__hip_bfloat16*)alloc((size_t)N * DIM * 2);
    __hip_bfloat16* hbuf = (__hip_bfloat16*)alloc((size_t)N * DIM * 2);  // bf16 intermediates
    float* stats      = (float*)alloc(3 * 512);     // 3 layer slots of 128 floats
    float* wlr        = (float*)alloc(3 * 128 * 4);
    short* wfrag      = (short*)alloc(3 * 8192 * 2); // [layer][hi/lo][4096] bf16

    int ntiles = (N + 15) >> 4;
    int attn_grid = (N + 15) / 16;
    if (attn_grid > 2048) attn_grid = 2048;   // persistent waves, grid-stride

    // CSR build (binned, once) + per-layer W prep (also zeros bucket_cnt/stats)
    wlr_kernel<<<3, 256, 0, stream>>>(
        (const float*)d_in[4],  (const float*)d_in[5],  (const float*)d_in[6],
        (const float*)d_in[10], (const float*)d_in[11], (const float*)d_in[12],
        (const float*)d_in[16], (const float*)d_in[17], (const float*)d_in[18],
        wlr, wfrag, bucket_cnt, stats);
    bin_count_kernel<<<256, 256, 0, stream>>>(dst, bucket_cnt, E);
    bucket_scan_kernel<<<1, MAXB, 0, stream>>>(bucket_cnt, bucket_off, bucket_fill);
    bin_scatter_kernel<<<(E + CHUNK - 1) / CHUNK, 256, 0, stream>>>(
        src, dst, bucket_off, bucket_fill, binned, E);
    csr_finalize_kernel<<<nbuck, 256, 0, stream>>>(binned, bucket_off, bucket_cnt,
                                                   row_ptr, src_sorted, N, E, nbuck);

    for (int l = 0; l < 3; l++) {
        const float* b    = (const float*)d_in[7 + 6 * l];
        const void* hin   = (l == 0) ? (const void*)nw : (const void*)hbuf;
        int in_bf16       = (l == 0) ? 0 : 1;
        void* hout        = (l == 2) ? (void*)d_out : (void*)hbuf;
        int out_bf16      = (l == 2) ? 0 : 1;
        float* stats_prev = (l == 0) ? stats : stats + (l - 1) * 128;
        float* stats_cur  = stats + l * 128;

        gemm64_mfma_kernel<<<(ntiles + 15) / 16, 256, 0, stream>>>(
            hin, in_bf16, wfrag + l * 8192,
            wlr + l * 128, wlr + l * 128 + 64,
            stats_prev,
            (l == 0) ? (const float*)d_in[8] : (const float*)d_in[8 + 6 * (l - 1)],
            (l == 0) ? (const float*)d_in[9] : (const float*)d_in[9 + 6 * (l - 1)],
            (l > 0) ? 1 : 0, invN,
            feat, el, er, N);
        attn_agg_kernel<<<attn_grid, 256, 0, stream>>>(row_ptr, src_sorted, el, er,
                                                       feat, b, hout, out_bf16, N);
        bn_stats_kernel<<<512, 256, 0, stream>>>(hout, out_bf16, stats_cur, N);
    }
    // final BatchNorm (no ELU) on d_out
    bn_apply_kernel<<<2048, 256, 0, stream>>>((float*)d_out, stats + 2 * 128,
                                              (const float*)d_in[8 + 12],
                                              (const float*)d_in[9 + 12],
                                              N, 0);
}

// Round 13
// 438.053 us; speedup vs baseline: 1.7580x; 1.0188x over previous
//
#include <hip/hip_runtime.h>
#include <hip/hip_bf16.h>
#include <math.h>

#define DIM 64
#define BSHIFT 9
#define BNODES 512   // 1 << BSHIFT
#define MAXB 256     // max coarse buckets (N <= 131072)
#define EPT 8
#define CHUNK 2048   // EPT * 256

typedef __attribute__((ext_vector_type(8))) short bf16x8;
typedef __attribute__((ext_vector_type(4))) float f32x4;

__device__ __forceinline__ short f2bf(float x) {
    union { __hip_bfloat16 b; short s; } u;
    u.b = __float2bfloat16(x);
    return u.s;
}
__device__ __forceinline__ float bf2f(short s) {
    return __uint_as_float(((unsigned)(unsigned short)s) << 16);
}

// ---------------- CSR build: binned sort, merged tail ----------------
// r8 lesson: scatter needs WRITE LOCALITY (direct-atomic scatter dirtied 64B
// lines randomly across 8 XCDs -> 107MB writeback). The binned design keeps
// writes in per-bucket ~32KB slices.

// r13: wlr + bin_count fused into one prep kernel. Count blocks write
// per-block histograms NON-atomically (hist[cb][bucket]) -- removes the
// bucket_cnt pre-zero ordering dependency; bucket_scan column-sums them.
__global__ __launch_bounds__(256) void prep_kernel(
    const float* __restrict__ W1, const float* __restrict__ al1, const float* __restrict__ ar1,
    const float* __restrict__ W2, const float* __restrict__ al2, const float* __restrict__ ar2,
    const float* __restrict__ W3, const float* __restrict__ al3, const float* __restrict__ ar3,
    float* __restrict__ wlr, short* __restrict__ wfrag, float* __restrict__ stats,
    const int* __restrict__ dst, int* __restrict__ hist, int E) {
    int t = threadIdx.x;
    if (blockIdx.x >= 3) {
        // bin_count part: 256 blocks, per-block LDS histogram -> hist slice
        __shared__ int h[MAXB];
        int cb = blockIdx.x - 3;
        h[t] = 0;
        __syncthreads();
        for (int i = cb * 256 + t; i < E; i += 256 * 256)
            atomicAdd(&h[dst[i] >> BSHIFT], 1);
        __syncthreads();
        hist[cb * MAXB + t] = h[t];
        return;
    }
    // wlr part (blocks 0-2): W frag packing + wl/wr; block 1 zeros stats
    const float* W  = (blockIdx.x == 0) ? W1  : (blockIdx.x == 1) ? W2  : W3;
    const float* al = (blockIdx.x == 0) ? al1 : (blockIdx.x == 1) ? al2 : al3;
    const float* ar = (blockIdx.x == 0) ? ar1 : (blockIdx.x == 1) ? ar2 : ar3;
    if (blockIdx.x == 1) { stats[t] = 0.f; if (t < 128) stats[256 + t] = 0.f; }  // 384 floats
    short* whi = wfrag + blockIdx.x * 8192;
    short* wlo = whi + 4096;
    for (int idx = t; idx < 4096; idx += 256) {
        int j = idx & 7, li = (idx >> 3) & 15, quad = (idx >> 7) & 3;
        int nt = (idx >> 9) & 3, ks = idx >> 11;
        int k = ks * 32 + quad * 8 + j, nn = nt * 16 + li;
        float w = W[k * 64 + nn];
        short hi = f2bf(w);
        whi[idx] = hi;
        wlo[idx] = f2bf(w - bf2f(hi));
    }
    if (t < 64) {
        float l = 0.f, r = 0.f;
        for (int nn = 0; nn < 64; nn++) {
            float w = W[t * 64 + nn];
            l = fmaf(w, al[nn], l);
            r = fmaf(w, ar[nn], r);
        }
        const float LOG2E = 1.4426950408889634f;
        wlr[blockIdx.x * 128 + t] = l * LOG2E;
        wlr[blockIdx.x * 128 + 64 + t] = r * LOG2E;
    }
}

// Column-sum the 256 per-block histograms, then exclusive scan.
__global__ void bucket_scan_kernel(const int* __restrict__ hist,
                                   int* __restrict__ bucket_cnt,
                                   int* __restrict__ bucket_off, int* __restrict__ bucket_fill) {
    __shared__ int s[MAXB];
    int t = threadIdx.x;
    int v = 0;
#pragma unroll 8
    for (int b = 0; b < 256; b++) v += hist[b * MAXB + t];
    bucket_cnt[t] = v;
    s[t] = v;
    __syncthreads();
    for (int off = 1; off < MAXB; off <<= 1) {
        int x = (t >= off) ? s[t - off] : 0;
        __syncthreads();
        s[t] += x;
        __syncthreads();
    }
    bucket_off[t] = s[t] - v;
    bucket_fill[t] = 0;
}

__global__ __launch_bounds__(256) void bin_scatter_kernel(
    const int* __restrict__ src, const int* __restrict__ dst,
    const int* __restrict__ bucket_off, int* __restrict__ bucket_fill,
    unsigned long long* __restrict__ binned, int E) {
    __shared__ int lcnt[MAXB];
    __shared__ int lbase[MAXB];
    int t = threadIdx.x;
    lcnt[t] = 0;
    __syncthreads();
    int base = blockIdx.x * CHUNK;
    unsigned long long pair[EPT];
    int slot[EPT];
#pragma unroll
    for (int j = 0; j < EPT; j++) {
        int idx = base + j * 256 + t;
        if (idx < E) {
            int s = src[idx], d = dst[idx];
            pair[j] = ((unsigned long long)(unsigned)d << 32) | (unsigned)s;
            slot[j] = atomicAdd(&lcnt[d >> BSHIFT], 1);
        } else {
            slot[j] = -1;
        }
    }
    __syncthreads();
    int c = lcnt[t];
    if (c) lbase[t] = atomicAdd(&bucket_fill[t], c);
    __syncthreads();
#pragma unroll
    for (int j = 0; j < EPT; j++) {
        if (slot[j] >= 0) {
            int b = (int)(pair[j] >> 32) >> BSHIFT;
            binned[(size_t)bucket_off[b] + lbase[b] + slot[j]] = pair[j];
        }
    }
}

// One block per bucket: count 512 node degrees in LDS, local exclusive scan,
// write row_ptr (global = bucket_off[b] + excl), scatter src into the
// bucket's contiguous src_sorted slice (~32KB window -> write locality).
__global__ __launch_bounds__(256) void csr_finalize_kernel(
    const unsigned long long* __restrict__ binned, const int* __restrict__ bucket_off,
    const int* __restrict__ bucket_cnt, int* __restrict__ row_ptr,
    int* __restrict__ src_sorted, int N, int E, int nbuck) {
    __shared__ int cnt[BNODES];
    __shared__ int excl[BNODES];
    __shared__ int ps[256];
    int b = blockIdx.x, t = threadIdx.x;
    for (int i = t; i < BNODES; i += 256) cnt[i] = 0;
    __syncthreads();
    int s0 = bucket_off[b], c = bucket_cnt[b];
    for (int i = t; i < c; i += 256)
        atomicAdd(&cnt[(int)(binned[(size_t)s0 + i] >> 32) & (BNODES - 1)], 1);
    __syncthreads();
    // exclusive scan over 512 via pairs (256 threads)
    int a0 = cnt[2 * t], a1 = cnt[2 * t + 1];
    int pairsum = a0 + a1;
    ps[t] = pairsum;
    __syncthreads();
    for (int off = 1; off < 256; off <<= 1) {
        int x = (t >= off) ? ps[t - off] : 0;
        __syncthreads();
        ps[t] += x;
        __syncthreads();
    }
    int run = ps[t] - pairsum;          // exclusive pair prefix
    excl[2 * t] = run;
    excl[2 * t + 1] = run + a0;
    __syncthreads();
    int nbase = b << BSHIFT;
    for (int i = t; i < BNODES; i += 256)
        if (nbase + i < N) row_ptr[nbase + i] = s0 + excl[i];
    if (b == nbuck - 1 && t == 0) row_ptr[N] = E;
    // reuse cnt as fill
    for (int i = t; i < BNODES; i += 256) cnt[i] = 0;
    __syncthreads();
    for (int i = t; i < c; i += 256) {
        unsigned long long p = binned[(size_t)s0 + i];
        int d = (int)(p >> 32) & (BNODES - 1);
        int pos = excl[d] + atomicAdd(&cnt[d], 1);
        src_sorted[(size_t)s0 + pos] = (int)(p & 0xffffffffu);
    }
}

// ---------------- per-layer kernels ----------------

// MFMA GEMM: feat(bf16) = bnelu(h) @ W ; el = act.wl ; er = act.wr
// Input h may be bf16 (intermediate layers). 4 tiles/wave (r12-proven).
__global__ __launch_bounds__(256) void gemm64_mfma_kernel(
    const void* __restrict__ hvoid, int in_bf16, const short* __restrict__ wfrag_l,
    const float* __restrict__ wl, const float* __restrict__ wr,
    const float* __restrict__ stats, const float* __restrict__ g,
    const float* __restrict__ beta, int do_bn, float invN,
    __hip_bfloat16* __restrict__ feat, float* __restrict__ el, float* __restrict__ er,
    int n) {
    int t = threadIdx.x;
    int lane = t & 63;
    int li = lane & 15;
    int quad = lane >> 4;
    int wv = t >> 6;

    const short* whi = wfrag_l;
    const short* wlo = wfrag_l + 4096;
    bf16x8 b_hi[2][4], b_lo[2][4];
#pragma unroll
    for (int ks = 0; ks < 2; ks++)
#pragma unroll
        for (int nt = 0; nt < 4; nt++) {
            int base = (((ks * 4 + nt) * 4 + quad) * 16 + li) * 8;
            b_hi[ks][nt] = *(const bf16x8*)(whi + base);
            b_lo[ks][nt] = *(const bf16x8*)(wlo + base);
        }
    float wlv[2][8], wrv[2][8];
#pragma unroll
    for (int ks = 0; ks < 2; ks++)
#pragma unroll
        for (int j = 0; j < 8; j++) {
            wlv[ks][j] = wl[ks * 32 + quad * 8 + j];
            wrv[ks][j] = wr[ks * 32 + quad * 8 + j];
        }

    float sc[2][8], sh[2][8];
    if (do_bn) {
#pragma unroll
        for (int ks = 0; ks < 2; ks++)
#pragma unroll
            for (int j = 0; j < 8; j++) {
                int k = ks * 32 + quad * 8 + j;
                float mu = stats[k] * invN;
                float var = fmaf(-mu, mu, stats[64 + k] * invN);
                float inv = rsqrtf(var + 1e-5f) * g[k];
                sc[ks][j] = inv;
                sh[ks][j] = beta[k] - mu * inv;
            }
    }

    int ntiles = (n + 15) >> 4;
    for (int tile = blockIdx.x * 4 + wv; tile < ntiles; tile += gridDim.x * 4) {
        int m0 = tile << 4;
        int rrow = m0 + li;
        size_t rowbase = (size_t)((rrow < n) ? rrow : (n - 1)) * 64;
        bf16x8 a_hi[2], a_lo[2];
        float elp = 0.f, erp = 0.f;
#pragma unroll
        for (int ks = 0; ks < 2; ks++) {
            float x[8];
            if (in_bf16) {
                const unsigned short* rp = (const unsigned short*)hvoid + rowbase + ks * 32 + quad * 8;
                uint4 pv = *(const uint4*)rp;
                x[0] = bf2f((short)(pv.x & 0xffffu)); x[1] = bf2f((short)(pv.x >> 16));
                x[2] = bf2f((short)(pv.y & 0xffffu)); x[3] = bf2f((short)(pv.y >> 16));
                x[4] = bf2f((short)(pv.z & 0xffffu)); x[5] = bf2f((short)(pv.z >> 16));
                x[6] = bf2f((short)(pv.w & 0xffffu)); x[7] = bf2f((short)(pv.w >> 16));
            } else {
                const float* rp = (const float*)hvoid + rowbase + ks * 32 + quad * 8;
                float4 v0 = *(const float4*)rp;
                float4 v1 = *(const float4*)(rp + 4);
                x[0] = v0.x; x[1] = v0.y; x[2] = v0.z; x[3] = v0.w;
                x[4] = v1.x; x[5] = v1.y; x[6] = v1.z; x[7] = v1.w;
            }
#pragma unroll
            for (int j = 0; j < 8; j++) {
                float v = x[j];
                if (do_bn) {
                    v = fmaf(v, sc[ks][j], sh[ks][j]);
                    if (v < 0.f) v = expm1f(v);   // ELU
                }
                elp = fmaf(v, wlv[ks][j], elp);
                erp = fmaf(v, wrv[ks][j], erp);
                short hi = f2bf(v);
                a_hi[ks][j] = hi;
                a_lo[ks][j] = f2bf(v - bf2f(hi));
            }
        }
        elp += __shfl_xor(elp, 16, 64);
        elp += __shfl_xor(elp, 32, 64);
        erp += __shfl_xor(erp, 16, 64);
        erp += __shfl_xor(erp, 32, 64);
        if (lane < 16 && m0 + li < n) {
            el[m0 + li] = elp;
            er[m0 + li] = erp;
        }
        f32x4 acc[4];
#pragma unroll
        for (int nt = 0; nt < 4; nt++) acc[nt] = (f32x4){0.f, 0.f, 0.f, 0.f};
#pragma unroll
        for (int ks = 0; ks < 2; ks++)
#pragma unroll
            for (int nt = 0; nt < 4; nt++) {
                acc[nt] = __builtin_amdgcn_mfma_f32_16x16x32_bf16(a_hi[ks], b_hi[ks][nt], acc[nt], 0, 0, 0);
                acc[nt] = __builtin_amdgcn_mfma_f32_16x16x32_bf16(a_lo[ks], b_hi[ks][nt], acc[nt], 0, 0, 0);
                acc[nt] = __builtin_amdgcn_mfma_f32_16x16x32_bf16(a_hi[ks], b_lo[ks][nt], acc[nt], 0, 0, 0);
            }
#pragma unroll
        for (int nt = 0; nt < 4; nt++)
#pragma unroll
            for (int reg = 0; reg < 4; reg++) {
                int wrow = m0 + quad * 4 + reg;
                if (wrow < n) {
                    union { __hip_bfloat16 b; short s; } u;
                    u.s = f2bf(acc[nt][reg]);
                    feat[(size_t)wrow * 64 + nt * 16 + li] = u.b;
                }
            }
    }
}

// Fused edge-score + softmax + weighted aggregate. r6 structure, r12
// persistent-wave grid (2048 co-resident blocks, grid-stride) -- proven 47us.
#define AGG_LOAD(P, ELV, POS)                                  \
    {                                                          \
        int idx = (POS) + q;                                   \
        bool v = idx < end;                                    \
        int idc = v ? idx : end - 1;                           \
        int sn = src_sorted[idc];                              \
        float ev = el[sn];                                     \
        ELV = v ? ev : -INFINITY;                              \
        P = featv[(size_t)sn * 8 + li];                        \
    }

#define AGG_CHUNK(P, ELV)                                      \
    {                                                          \
        float e = ELV + er_n;                                  \
        e = fmaxf(e, 0.2f * e);                                \
        float w = exp2f(e);                                    \
        s += w;                                                \
        a0 = fmaf(w, __uint_as_float(P.x << 16), a0);          \
        a1 = fmaf(w, __uint_as_float(P.x & 0xffff0000u), a1);  \
        a2 = fmaf(w, __uint_as_float(P.y << 16), a2);          \
        a3 = fmaf(w, __uint_as_float(P.y & 0xffff0000u), a3);  \
        a4 = fmaf(w, __uint_as_float(P.z << 16), a4);          \
        a5 = fmaf(w, __uint_as_float(P.z & 0xffff0000u), a5);  \
        a6 = fmaf(w, __uint_as_float(P.w << 16), a6);          \
        a7 = fmaf(w, __uint_as_float(P.w & 0xffff0000u), a7);  \
    }

__global__ __launch_bounds__(256) void attn_agg_kernel(
    const int* __restrict__ row_ptr, const int* __restrict__ src_sorted,
    const float* __restrict__ el, const float* __restrict__ er,
    const __hip_bfloat16* __restrict__ feat, const float* __restrict__ bias,
    void* __restrict__ outv, int out_bf16, int n) {
    int t = threadIdx.x, lane = t & 63;
    int q = lane >> 3;        // edge slot 0..7
    int li = lane & 7;        // dim octet 0..7
    int d = li * 8 + ((q & 1) << 2) + (q & 2) + ((q >> 2) & 1);  // this lane's dim
    float bias_d = bias[d];
    const uint4* featv = (const uint4*)feat;

    for (int base = blockIdx.x * 16; base < n; base += gridDim.x * 16) {
        int node0 = base + (t >> 6) * 4;   // 4 nodes per wave per sweep
#pragma unroll
        for (int j = 0; j < 4; j++) {
            int node = node0 + j;
            if (node >= n) break;                      // wave-uniform
            int start = row_ptr[node], end = row_ptr[node + 1];
            float er_n = er[node];

            float s = 0.f;
            float a0 = 0.f, a1 = 0.f, a2 = 0.f, a3 = 0.f;
            float a4 = 0.f, a5 = 0.f, a6 = 0.f, a7 = 0.f;

            uint4 pA = {0u, 0u, 0u, 0u}, pB = {0u, 0u, 0u, 0u};
            float elA = -INFINITY, elB = -INFINITY;
            if (start < end) AGG_LOAD(pA, elA, start)
            if (start + 8 < end) AGG_LOAD(pB, elB, start + 8)
            for (int i = start; i < end; i += 16) {    // all branches wave-uniform
                AGG_CHUNK(pA, elA)
                if (i + 16 < end) AGG_LOAD(pA, elA, i + 16)
                if (i + 8 < end) {
                    AGG_CHUNK(pB, elB)
                    if (i + 24 < end) AGG_LOAD(pB, elB, i + 24)
                }
            }
            s += __shfl_xor(s, 8, 64);
            s += __shfl_xor(s, 16, 64);
            s += __shfl_xor(s, 32, 64);
            bool b0 = (q & 1) != 0;
            float t0 = __shfl_xor(a0, 8, 64), t1 = __shfl_xor(a1, 8, 64);
            float t2 = __shfl_xor(a2, 8, 64), t3 = __shfl_xor(a3, 8, 64);
            float t4 = __shfl_xor(a4, 8, 64), t5 = __shfl_xor(a5, 8, 64);
            float t6 = __shfl_xor(a6, 8, 64), t7 = __shfl_xor(a7, 8, 64);
            float x0 = b0 ? (a4 + t4) : (a0 + t0);
            float x1 = b0 ? (a5 + t5) : (a1 + t1);
            float y0 = b0 ? (a6 + t6) : (a2 + t2);
            float y1 = b0 ? (a7 + t7) : (a3 + t3);
            bool b1 = (q & 2) != 0;
            float u0 = __shfl_xor(x0, 16, 64), u1 = __shfl_xor(x1, 16, 64);
            float v0 = __shfl_xor(y0, 16, 64), v1 = __shfl_xor(y1, 16, 64);
            float z0 = b1 ? (y0 + v0) : (x0 + u0);
            float z1 = b1 ? (y1 + v1) : (x1 + u1);
            z0 += __shfl_xor(z0, 32, 64);
            z1 += __shfl_xor(z1, 32, 64);
            float val = ((q & 4) != 0) ? z1 : z0;
            float inv_s = (s > 0.f) ? 1.f / s : 0.f;
            float x = fmaf(val, inv_s, bias_d);
            if (out_bf16) {
                union { __hip_bfloat16 b; short s2; } u;
                u.s2 = f2bf(x);
                ((__hip_bfloat16*)outv)[(size_t)node * 64 + d] = u.b;
            } else {
                ((float*)outv)[(size_t)node * 64 + d] = x;
            }
        }
    }
}

// column sums / sumsq -- r13 VECTORIZED (G13): thread (row-slot rs, octet oc)
// loads 8 dims per row via one uint4 (bf16) / two float4 (fp32); 8 acc pairs
// per lane; LDS epilogue. 8x fewer load instructions than the scalar version.
__global__ __launch_bounds__(256) void bn_stats_kernel(const void* __restrict__ hvoid,
                                                       int in_bf16,
                                                       float* __restrict__ stats, int n) {
    __shared__ float lp[256][8];
    __shared__ float lq[256][8];
    int t = threadIdx.x;
    int rs = t >> 3;       // row slot 0..31
    int oc = t & 7;        // dim octet 0..7 (dims oc*8 .. oc*8+7)
    float s[8], ss[8];
#pragma unroll
    for (int j = 0; j < 8; j++) { s[j] = 0.f; ss[j] = 0.f; }
    for (int row = blockIdx.x * 32 + rs; row < n; row += gridDim.x * 32) {
        float x[8];
        if (in_bf16) {
            const unsigned short* rp = (const unsigned short*)hvoid + (size_t)row * 64 + oc * 8;
            uint4 pv = *(const uint4*)rp;
            x[0] = bf2f((short)(pv.x & 0xffffu)); x[1] = bf2f((short)(pv.x >> 16));
            x[2] = bf2f((short)(pv.y & 0xffffu)); x[3] = bf2f((short)(pv.y >> 16));
            x[4] = bf2f((short)(pv.z & 0xffffu)); x[5] = bf2f((short)(pv.z >> 16));
            x[6] = bf2f((short)(pv.w & 0xffffu)); x[7] = bf2f((short)(pv.w >> 16));
        } else {
            const float* rp = (const float*)hvoid + (size_t)row * 64 + oc * 8;
            float4 v0 = *(const float4*)rp;
            float4 v1 = *(const float4*)(rp + 4);
            x[0] = v0.x; x[1] = v0.y; x[2] = v0.z; x[3] = v0.w;
            x[4] = v1.x; x[5] = v1.y; x[6] = v1.z; x[7] = v1.w;
        }
#pragma unroll
        for (int j = 0; j < 8; j++) {
            s[j] += x[j];
            ss[j] = fmaf(x[j], x[j], ss[j]);
        }
    }
#pragma unroll
    for (int j = 0; j < 8; j++) { lp[t][j] = s[j]; lq[t][j] = ss[j]; }
    __syncthreads();
    if (t < 64) {
        // dim d = t; partials live at threads r2*8 + (t>>3), entry (t&7)
        int o = t >> 3, j = t & 7;
        float a = 0.f, b = 0.f;
#pragma unroll 8
        for (int r2 = 0; r2 < 32; r2++) {
            a += lp[r2 * 8 + o][j];
            b += lq[r2 * 8 + o][j];
        }
        atomicAdd(&stats[t], a);
        atomicAdd(&stats[64 + t], b);
    }
}

// final BatchNorm -- r13: float4 vectorized (4 dims per thread per iter)
__global__ void bn_apply_kernel(float* __restrict__ h, const float* __restrict__ stats,
                                const float* __restrict__ g, const float* __restrict__ beta,
                                int n, int do_elu) {
    int i = blockIdx.x * blockDim.x + threadIdx.x;
    int total4 = n * 16;                 // n*64/4 float4s
    int stride = gridDim.x * blockDim.x;
    float invN = 1.f / (float)n;
    for (; i < total4; i += stride) {
        float4 v = ((const float4*)h)[i];
        int c0 = (i & 15) * 4;           // dims c0..c0+3
        float vv[4] = {v.x, v.y, v.z, v.w};
#pragma unroll
        for (int k = 0; k < 4; k++) {
            int c = c0 + k;
            float mu = stats[c] * invN;
            float var = fmaf(-mu, mu, stats[64 + c] * invN);
            float x = (vv[k] - mu) * rsqrtf(var + 1e-5f) * g[c] + beta[c];
            if (do_elu && x < 0.f) x = expm1f(x);
            vv[k] = x;
        }
        float4 o = {vv[0], vv[1], vv[2], vv[3]};
        ((float4*)h)[i] = o;
    }
}

// ---------------- launch ----------------

extern "C" void kernel_launch(void* const* d_in, const int* in_sizes, int n_in,
                              void* d_out, int out_size, void* d_ws, size_t ws_size,
                              hipStream_t stream) {
    const float* nw = (const float*)d_in[0];
    const int* src = (const int*)d_in[2];
    const int* dst = (const int*)d_in[3];
    const int N = in_sizes[0] / DIM;
    const int E = in_sizes[2];
    const float invN = 1.f / (float)N;
    const int nbuck = (N + BNODES - 1) >> BSHIFT;

    char* ws = (char*)d_ws;
    size_t off = 0;
    auto alloc = [&](size_t bytes) -> void* {
        void* p = ws + off;
        off += (bytes + 255) & ~(size_t)255;
        return p;
    };
    int* row_ptr      = (int*)alloc(((size_t)N + 1) * 4);
    int* bucket_cnt   = (int*)alloc(MAXB * 4);
    int* bucket_off   = (int*)alloc(MAXB * 4);
    int* bucket_fill  = (int*)alloc(MAXB * 4);
    int* hist         = (int*)alloc((size_t)MAXB * 256 * 4);   // per-block histograms
    unsigned long long* binned = (unsigned long long*)alloc((size_t)E * 8);
    int* src_sorted   = (int*)alloc((size_t)E * 4);
    float* el         = (float*)alloc((size_t)N * 4);
    float* er         = (float*)alloc((size_t)N * 4);
    __hip_bfloat16* feat = (__hip_bfloat16*)alloc((size_t)N * DIM * 2);
    __hip_bfloat16* hbuf = (__hip_bfloat16*)alloc((size_t)N * DIM * 2);  // bf16 intermediates
    float* stats      = (float*)alloc(3 * 512);     // 3 layer slots of 128 floats
    float* wlr        = (float*)alloc(3 * 128 * 4);
    short* wfrag      = (short*)alloc(3 * 8192 * 2); // [layer][hi/lo][4096] bf16

    int ntiles = (N + 15) >> 4;
    int attn_grid = (N + 15) / 16;
    if (attn_grid > 2048) attn_grid = 2048;   // persistent waves, grid-stride

    // prep: W frags + wl/wr + stats zero + per-block dst histograms (fused)
    prep_kernel<<<3 + 256, 256, 0, stream>>>(
        (const float*)d_in[4],  (const float*)d_in[5],  (const float*)d_in[6],
        (const float*)d_in[10], (const float*)d_in[11], (const float*)d_in[12],
        (const float*)d_in[16], (const float*)d_in[17], (const float*)d_in[18],
        wlr, wfrag, stats, dst, hist, E);
    bucket_scan_kernel<<<1, MAXB, 0, stream>>>(hist, bucket_cnt, bucket_off, bucket_fill);
    bin_scatter_kernel<<<(E + CHUNK - 1) / CHUNK, 256, 0, stream>>>(
        src, dst, bucket_off, bucket_fill, binned, E);
    csr_finalize_kernel<<<nbuck, 256, 0, stream>>>(binned, bucket_off, bucket_cnt,
                                                   row_ptr, src_sorted, N, E, nbuck);

    for (int l = 0; l < 3; l++) {
        const float* b    = (const float*)d_in[7 + 6 * l];
        const void* hin   = (l == 0) ? (const void*)nw : (const void*)hbuf;
        int in_bf16       = (l == 0) ? 0 : 1;
        void* hout        = (l == 2) ? (void*)d_out : (void*)hbuf;
        int out_bf16      = (l == 2) ? 0 : 1;
        float* stats_prev = (l == 0) ? stats : stats + (l - 1) * 128;
        float* stats_cur  = stats + l * 128;

        gemm64_mfma_kernel<<<(ntiles + 15) / 16, 256, 0, stream>>>(
            hin, in_bf16, wfrag + l * 8192,
            wlr + l * 128, wlr + l * 128 + 64,
            stats_prev,
            (l == 0) ? (const float*)d_in[8] : (const float*)d_in[8 + 6 * (l - 1)],
            (l == 0) ? (const float*)d_in[9] : (const float*)d_in[9 + 6 * (l - 1)],
            (l > 0) ? 1 : 0, invN,
            feat, el, er, N);
        attn_agg_kernel<<<attn_grid, 256, 0, stream>>>(row_ptr, src_sorted, el, er,
                                                       feat, b, hout, out_bf16, N);
        bn_stats_kernel<<<512, 256, 0, stream>>>(hout, out_bf16, stats_cur, N);
    }
    // final BatchNorm (no ELU) on d_out
    bn_apply_kernel<<<2048, 256, 0, stream>>>((float*)d_out, stats + 2 * 128,
                                              (const float*)d_in[8 + 12],
                                              (const float*)d_in[9 + 12],
                                              N, 0);
}

// Round 15
// 434.768 us; speedup vs baseline: 1.7713x; 1.0076x over previous
//
#include <hip/hip_runtime.h>
#include <hip/hip_bf16.h>
#include <math.h>

#define DIM 64
#define BSHIFT 9
#define BNODES 512   // 1 << BSHIFT
#define MAXB 256     // max coarse buckets (N <= 131072)
#define EPT 8
#define CHUNK 2048   // EPT * 256

typedef __attribute__((ext_vector_type(8))) short bf16x8;
typedef __attribute__((ext_vector_type(4))) float f32x4;

__device__ __forceinline__ short f2bf(float x) {
    union { __hip_bfloat16 b; short s; } u;
    u.b = __float2bfloat16(x);
    return u.s;
}
__device__ __forceinline__ float bf2f(short s) {
    return __uint_as_float(((unsigned)(unsigned short)s) << 16);
}

// ---------------- CSR build: binned sort, merged tail ----------------
// r8 lesson: scatter needs WRITE LOCALITY (direct-atomic scatter dirtied 64B
// lines randomly across 8 XCDs -> 107MB writeback). The binned design keeps
// writes in per-bucket ~32KB slices.

// r13: wlr + bin_count fused into one prep kernel. Count blocks write
// per-block histograms NON-atomically (hist[cb][bucket]) -- removes the
// bucket_cnt pre-zero ordering dependency; bucket_scan column-sums them.
__global__ __launch_bounds__(256) void prep_kernel(
    const float* __restrict__ W1, const float* __restrict__ al1, const float* __restrict__ ar1,
    const float* __restrict__ W2, const float* __restrict__ al2, const float* __restrict__ ar2,
    const float* __restrict__ W3, const float* __restrict__ al3, const float* __restrict__ ar3,
    float* __restrict__ wlr, short* __restrict__ wfrag, float* __restrict__ stats,
    const int* __restrict__ dst, int* __restrict__ hist, int E) {
    int t = threadIdx.x;
    if (blockIdx.x >= 3) {
        // bin_count part: 256 blocks, per-block LDS histogram -> hist slice
        __shared__ int h[MAXB];
        int cb = blockIdx.x - 3;
        h[t] = 0;
        __syncthreads();
        for (int i = cb * 256 + t; i < E; i += 256 * 256)
            atomicAdd(&h[dst[i] >> BSHIFT], 1);
        __syncthreads();
        hist[cb * MAXB + t] = h[t];
        return;
    }
    // wlr part (blocks 0-2): W frag packing + wl/wr; block 1 zeros stats
    const float* W  = (blockIdx.x == 0) ? W1  : (blockIdx.x == 1) ? W2  : W3;
    const float* al = (blockIdx.x == 0) ? al1 : (blockIdx.x == 1) ? al2 : al3;
    const float* ar = (blockIdx.x == 0) ? ar1 : (blockIdx.x == 1) ? ar2 : ar3;
    if (blockIdx.x == 1) { stats[t] = 0.f; if (t < 128) stats[256 + t] = 0.f; }  // 384 floats
    short* whi = wfrag + blockIdx.x * 8192;
    short* wlo = whi + 4096;
    for (int idx = t; idx < 4096; idx += 256) {
        int j = idx & 7, li = (idx >> 3) & 15, quad = (idx >> 7) & 3;
        int nt = (idx >> 9) & 3, ks = idx >> 11;
        int k = ks * 32 + quad * 8 + j, nn = nt * 16 + li;
        float w = W[k * 64 + nn];
        short hi = f2bf(w);
        whi[idx] = hi;
        wlo[idx] = f2bf(w - bf2f(hi));
    }
    if (t < 64) {
        float l = 0.f, r = 0.f;
        for (int nn = 0; nn < 64; nn++) {
            float w = W[t * 64 + nn];
            l = fmaf(w, al[nn], l);
            r = fmaf(w, ar[nn], r);
        }
        const float LOG2E = 1.4426950408889634f;
        wlr[blockIdx.x * 128 + t] = l * LOG2E;
        wlr[blockIdx.x * 128 + 64 + t] = r * LOG2E;
    }
}

// Column-sum the 256 per-block histograms, then exclusive scan.
__global__ void bucket_scan_kernel(const int* __restrict__ hist,
                                   int* __restrict__ bucket_cnt,
                                   int* __restrict__ bucket_off, int* __restrict__ bucket_fill) {
    __shared__ int s[MAXB];
    int t = threadIdx.x;
    int v = 0;
#pragma unroll 8
    for (int b = 0; b < 256; b++) v += hist[b * MAXB + t];
    bucket_cnt[t] = v;
    s[t] = v;
    __syncthreads();
    for (int off = 1; off < MAXB; off <<= 1) {
        int x = (t >= off) ? s[t - off] : 0;
        __syncthreads();
        s[t] += x;
        __syncthreads();
    }
    bucket_off[t] = s[t] - v;
    bucket_fill[t] = 0;
}

__global__ __launch_bounds__(256) void bin_scatter_kernel(
    const int* __restrict__ src, const int* __restrict__ dst,
    const int* __restrict__ bucket_off, int* __restrict__ bucket_fill,
    unsigned long long* __restrict__ binned, int E) {
    __shared__ int lcnt[MAXB];
    __shared__ int lbase[MAXB];
    int t = threadIdx.x;
    lcnt[t] = 0;
    __syncthreads();
    int base = blockIdx.x * CHUNK;
    unsigned long long pair[EPT];
    int slot[EPT];
#pragma unroll
    for (int j = 0; j < EPT; j++) {
        int idx = base + j * 256 + t;
        if (idx < E) {
            int s = src[idx], d = dst[idx];
            pair[j] = ((unsigned long long)(unsigned)d << 32) | (unsigned)s;
            slot[j] = atomicAdd(&lcnt[d >> BSHIFT], 1);
        } else {
            slot[j] = -1;
        }
    }
    __syncthreads();
    int c = lcnt[t];
    if (c) lbase[t] = atomicAdd(&bucket_fill[t], c);
    __syncthreads();
#pragma unroll
    for (int j = 0; j < EPT; j++) {
        if (slot[j] >= 0) {
            int b = (int)(pair[j] >> 32) >> BSHIFT;
            binned[(size_t)bucket_off[b] + lbase[b] + slot[j]] = pair[j];
        }
    }
}

// One block per bucket: count 512 node degrees in LDS, local exclusive scan,
// write row_ptr (global = bucket_off[b] + excl), scatter src into the
// bucket's contiguous src_sorted slice (~32KB window -> write locality).
__global__ __launch_bounds__(256) void csr_finalize_kernel(
    const unsigned long long* __restrict__ binned, const int* __restrict__ bucket_off,
    const int* __restrict__ bucket_cnt, int* __restrict__ row_ptr,
    int* __restrict__ src_sorted, int N, int E, int nbuck) {
    __shared__ int cnt[BNODES];
    __shared__ int excl[BNODES];
    __shared__ int ps[256];
    int b = blockIdx.x, t = threadIdx.x;
    for (int i = t; i < BNODES; i += 256) cnt[i] = 0;
    __syncthreads();
    int s0 = bucket_off[b], c = bucket_cnt[b];
    for (int i = t; i < c; i += 256)
        atomicAdd(&cnt[(int)(binned[(size_t)s0 + i] >> 32) & (BNODES - 1)], 1);
    __syncthreads();
    // exclusive scan over 512 via pairs (256 threads)
    int a0 = cnt[2 * t], a1 = cnt[2 * t + 1];
    int pairsum = a0 + a1;
    ps[t] = pairsum;
    __syncthreads();
    for (int off = 1; off < 256; off <<= 1) {
        int x = (t >= off) ? ps[t - off] : 0;
        __syncthreads();
        ps[t] += x;
        __syncthreads();
    }
    int run = ps[t] - pairsum;          // exclusive pair prefix
    excl[2 * t] = run;
    excl[2 * t + 1] = run + a0;
    __syncthreads();
    int nbase = b << BSHIFT;
    for (int i = t; i < BNODES; i += 256)
        if (nbase + i < N) row_ptr[nbase + i] = s0 + excl[i];
    if (b == nbuck - 1 && t == 0) row_ptr[N] = E;
    // reuse cnt as fill
    for (int i = t; i < BNODES; i += 256) cnt[i] = 0;
    __syncthreads();
    for (int i = t; i < c; i += 256) {
        unsigned long long p = binned[(size_t)s0 + i];
        int d = (int)(p >> 32) & (BNODES - 1);
        int pos = excl[d] + atomicAdd(&cnt[d], 1);
        src_sorted[(size_t)s0 + pos] = (int)(p & 0xffffffffu);
    }
}

// ---------------- per-layer kernels ----------------

// MFMA GEMM: feat(bf16) = bnelu(h) @ W ; el = act.wl ; er = act.wr
// Input h may be bf16 (intermediate layers). 4 tiles/wave (r12-proven).
__global__ __launch_bounds__(256) void gemm64_mfma_kernel(
    const void* __restrict__ hvoid, int in_bf16, const short* __restrict__ wfrag_l,
    const float* __restrict__ wl, const float* __restrict__ wr,
    const float* __restrict__ stats, const float* __restrict__ g,
    const float* __restrict__ beta, int do_bn, float invN,
    __hip_bfloat16* __restrict__ feat, float* __restrict__ el, float* __restrict__ er,
    int n) {
    int t = threadIdx.x;
    int lane = t & 63;
    int li = lane & 15;
    int quad = lane >> 4;
    int wv = t >> 6;

    const short* whi = wfrag_l;
    const short* wlo = wfrag_l + 4096;
    bf16x8 b_hi[2][4], b_lo[2][4];
#pragma unroll
    for (int ks = 0; ks < 2; ks++)
#pragma unroll
        for (int nt = 0; nt < 4; nt++) {
            int base = (((ks * 4 + nt) * 4 + quad) * 16 + li) * 8;
            b_hi[ks][nt] = *(const bf16x8*)(whi + base);
            b_lo[ks][nt] = *(const bf16x8*)(wlo + base);
        }
    float wlv[2][8], wrv[2][8];
#pragma unroll
    for (int ks = 0; ks < 2; ks++)
#pragma unroll
        for (int j = 0; j < 8; j++) {
            wlv[ks][j] = wl[ks * 32 + quad * 8 + j];
            wrv[ks][j] = wr[ks * 32 + quad * 8 + j];
        }

    float sc[2][8], sh[2][8];
    if (do_bn) {
#pragma unroll
        for (int ks = 0; ks < 2; ks++)
#pragma unroll
            for (int j = 0; j < 8; j++) {
                int k = ks * 32 + quad * 8 + j;
                float mu = stats[k] * invN;
                float var = fmaf(-mu, mu, stats[64 + k] * invN);
                float inv = rsqrtf(var + 1e-5f) * g[k];
                sc[ks][j] = inv;
                sh[ks][j] = beta[k] - mu * inv;
            }
    }

    int ntiles = (n + 15) >> 4;
    for (int tile = blockIdx.x * 4 + wv; tile < ntiles; tile += gridDim.x * 4) {
        int m0 = tile << 4;
        int rrow = m0 + li;
        size_t rowbase = (size_t)((rrow < n) ? rrow : (n - 1)) * 64;
        bf16x8 a_hi[2], a_lo[2];
        float elp = 0.f, erp = 0.f;
#pragma unroll
        for (int ks = 0; ks < 2; ks++) {
            float x[8];
            if (in_bf16) {
                const unsigned short* rp = (const unsigned short*)hvoid + rowbase + ks * 32 + quad * 8;
                uint4 pv = *(const uint4*)rp;
                x[0] = bf2f((short)(pv.x & 0xffffu)); x[1] = bf2f((short)(pv.x >> 16));
                x[2] = bf2f((short)(pv.y & 0xffffu)); x[3] = bf2f((short)(pv.y >> 16));
                x[4] = bf2f((short)(pv.z & 0xffffu)); x[5] = bf2f((short)(pv.z >> 16));
                x[6] = bf2f((short)(pv.w & 0xffffu)); x[7] = bf2f((short)(pv.w >> 16));
            } else {
                const float* rp = (const float*)hvoid + rowbase + ks * 32 + quad * 8;
                float4 v0 = *(const float4*)rp;
                float4 v1 = *(const float4*)(rp + 4);
                x[0] = v0.x; x[1] = v0.y; x[2] = v0.z; x[3] = v0.w;
                x[4] = v1.x; x[5] = v1.y; x[6] = v1.z; x[7] = v1.w;
            }
#pragma unroll
            for (int j = 0; j < 8; j++) {
                float v = x[j];
                if (do_bn) {
                    v = fmaf(v, sc[ks][j], sh[ks][j]);
                    if (v < 0.f) v = expm1f(v);   // ELU
                }
                elp = fmaf(v, wlv[ks][j], elp);
                erp = fmaf(v, wrv[ks][j], erp);
                short hi = f2bf(v);
                a_hi[ks][j] = hi;
                a_lo[ks][j] = f2bf(v - bf2f(hi));
            }
        }
        elp += __shfl_xor(elp, 16, 64);
        elp += __shfl_xor(elp, 32, 64);
        erp += __shfl_xor(erp, 16, 64);
        erp += __shfl_xor(erp, 32, 64);
        if (lane < 16 && m0 + li < n) {
            el[m0 + li] = elp;
            er[m0 + li] = erp;
        }
        f32x4 acc[4];
#pragma unroll
        for (int nt = 0; nt < 4; nt++) acc[nt] = (f32x4){0.f, 0.f, 0.f, 0.f};
#pragma unroll
        for (int ks = 0; ks < 2; ks++)
#pragma unroll
            for (int nt = 0; nt < 4; nt++) {
                acc[nt] = __builtin_amdgcn_mfma_f32_16x16x32_bf16(a_hi[ks], b_hi[ks][nt], acc[nt], 0, 0, 0);
                acc[nt] = __builtin_amdgcn_mfma_f32_16x16x32_bf16(a_lo[ks], b_hi[ks][nt], acc[nt], 0, 0, 0);
                acc[nt] = __builtin_amdgcn_mfma_f32_16x16x32_bf16(a_hi[ks], b_lo[ks][nt], acc[nt], 0, 0, 0);
            }
#pragma unroll
        for (int nt = 0; nt < 4; nt++)
#pragma unroll
            for (int reg = 0; reg < 4; reg++) {
                int wrow = m0 + quad * 4 + reg;
                if (wrow < n) {
                    union { __hip_bfloat16 b; short s; } u;
                    u.s = f2bf(acc[nt][reg]);
                    feat[(size_t)wrow * 64 + nt * 16 + li] = u.b;
                }
            }
    }
}

// Fused edge-score + softmax + weighted aggregate. r6 structure, r12
// persistent-wave grid (2048 co-resident blocks, grid-stride) -- proven 46us.
#define AGG_LOAD(P, ELV, POS)                                  \
    {                                                          \
        int idx = (POS) + q;                                   \
        bool v = idx < end;                                    \
        int idc = v ? idx : end - 1;                           \
        int sn = src_sorted[idc];                              \
        float ev = el[sn];                                     \
        ELV = v ? ev : -INFINITY;                              \
        P = featv[(size_t)sn * 8 + li];                        \
    }

#define AGG_CHUNK(P, ELV)                                      \
    {                                                          \
        float e = ELV + er_n;                                  \
        e = fmaxf(e, 0.2f * e);                                \
        float w = exp2f(e);                                    \
        s += w;                                                \
        a0 = fmaf(w, __uint_as_float(P.x << 16), a0);          \
        a1 = fmaf(w, __uint_as_float(P.x & 0xffff0000u), a1);  \
        a2 = fmaf(w, __uint_as_float(P.y << 16), a2);          \
        a3 = fmaf(w, __uint_as_float(P.y & 0xffff0000u), a3);  \
        a4 = fmaf(w, __uint_as_float(P.z << 16), a4);          \
        a5 = fmaf(w, __uint_as_float(P.z & 0xffff0000u), a5);  \
        a6 = fmaf(w, __uint_as_float(P.w << 16), a6);          \
        a7 = fmaf(w, __uint_as_float(P.w & 0xffff0000u), a7);  \
    }

__global__ __launch_bounds__(256) void attn_agg_kernel(
    const int* __restrict__ row_ptr, const int* __restrict__ src_sorted,
    const float* __restrict__ el, const float* __restrict__ er,
    const __hip_bfloat16* __restrict__ feat, const float* __restrict__ bias,
    void* __restrict__ outv, int out_bf16, int n) {
    int t = threadIdx.x, lane = t & 63;
    int q = lane >> 3;        // edge slot 0..7
    int li = lane & 7;        // dim octet 0..7
    int d = li * 8 + ((q & 1) << 2) + (q & 2) + ((q >> 2) & 1);  // this lane's dim
    float bias_d = bias[d];
    const uint4* featv = (const uint4*)feat;

    for (int base = blockIdx.x * 16; base < n; base += gridDim.x * 16) {
        int node0 = base + (t >> 6) * 4;   // 4 nodes per wave per sweep
#pragma unroll
        for (int j = 0; j < 4; j++) {
            int node = node0 + j;
            if (node >= n) break;                      // wave-uniform
            int start = row_ptr[node], end = row_ptr[node + 1];
            float er_n = er[node];

            float s = 0.f;
            float a0 = 0.f, a1 = 0.f, a2 = 0.f, a3 = 0.f;
            float a4 = 0.f, a5 = 0.f, a6 = 0.f, a7 = 0.f;

            uint4 pA = {0u, 0u, 0u, 0u}, pB = {0u, 0u, 0u, 0u};
            float elA = -INFINITY, elB = -INFINITY;
            if (start < end) AGG_LOAD(pA, elA, start)
            if (start + 8 < end) AGG_LOAD(pB, elB, start + 8)
            for (int i = start; i < end; i += 16) {    // all branches wave-uniform
                AGG_CHUNK(pA, elA)
                if (i + 16 < end) AGG_LOAD(pA, elA, i + 16)
                if (i + 8 < end) {
                    AGG_CHUNK(pB, elB)
                    if (i + 24 < end) AGG_LOAD(pB, elB, i + 24)
                }
            }
            s += __shfl_xor(s, 8, 64);
            s += __shfl_xor(s, 16, 64);
            s += __shfl_xor(s, 32, 64);
            bool b0 = (q & 1) != 0;
            float t0 = __shfl_xor(a0, 8, 64), t1 = __shfl_xor(a1, 8, 64);
            float t2 = __shfl_xor(a2, 8, 64), t3 = __shfl_xor(a3, 8, 64);
            float t4 = __shfl_xor(a4, 8, 64), t5 = __shfl_xor(a5, 8, 64);
            float t6 = __shfl_xor(a6, 8, 64), t7 = __shfl_xor(a7, 8, 64);
            float x0 = b0 ? (a4 + t4) : (a0 + t0);
            float x1 = b0 ? (a5 + t5) : (a1 + t1);
            float y0 = b0 ? (a6 + t6) : (a2 + t2);
            float y1 = b0 ? (a7 + t7) : (a3 + t3);
            bool b1 = (q & 2) != 0;
            float u0 = __shfl_xor(x0, 16, 64), u1 = __shfl_xor(x1, 16, 64);
            float v0 = __shfl_xor(y0, 16, 64), v1 = __shfl_xor(y1, 16, 64);
            float z0 = b1 ? (y0 + v0) : (x0 + u0);
            float z1 = b1 ? (y1 + v1) : (x1 + u1);
            z0 += __shfl_xor(z0, 32, 64);
            z1 += __shfl_xor(z1, 32, 64);
            float val = ((q & 4) != 0) ? z1 : z0;
            float inv_s = (s > 0.f) ? 1.f / s : 0.f;
            float x = fmaf(val, inv_s, bias_d);
            if (out_bf16) {
                union { __hip_bfloat16 b; short s2; } u;
                u.s2 = f2bf(x);
                ((__hip_bfloat16*)outv)[(size_t)node * 64 + d] = u.b;
            } else {
                ((float*)outv)[(size_t)node * 64 + d] = x;
            }
        }
    }
}

// column sums / sumsq -- r13 VECTORIZED (G13): thread (row-slot rs, octet oc)
// loads 8 dims per row via one uint4 (bf16) / two float4 (fp32); 8 acc pairs
// per lane; LDS epilogue. 8x fewer load instructions than the scalar version.
__global__ __launch_bounds__(256) void bn_stats_kernel(const void* __restrict__ hvoid,
                                                       int in_bf16,
                                                       float* __restrict__ stats, int n) {
    __shared__ float lp[256][8];
    __shared__ float lq[256][8];
    int t = threadIdx.x;
    int rs = t >> 3;       // row slot 0..31
    int oc = t & 7;        // dim octet 0..7 (dims oc*8 .. oc*8+7)
    float s[8], ss[8];
#pragma unroll
    for (int j = 0; j < 8; j++) { s[j] = 0.f; ss[j] = 0.f; }
    for (int row = blockIdx.x * 32 + rs; row < n; row += gridDim.x * 32) {
        float x[8];
        if (in_bf16) {
            const unsigned short* rp = (const unsigned short*)hvoid + (size_t)row * 64 + oc * 8;
            uint4 pv = *(const uint4*)rp;
            x[0] = bf2f((short)(pv.x & 0xffffu)); x[1] = bf2f((short)(pv.x >> 16));
            x[2] = bf2f((short)(pv.y & 0xffffu)); x[3] = bf2f((short)(pv.y >> 16));
            x[4] = bf2f((short)(pv.z & 0xffffu)); x[5] = bf2f((short)(pv.z >> 16));
            x[6] = bf2f((short)(pv.w & 0xffffu)); x[7] = bf2f((short)(pv.w >> 16));
        } else {
            const float* rp = (const float*)hvoid + (size_t)row * 64 + oc * 8;
            float4 v0 = *(const float4*)rp;
            float4 v1 = *(const float4*)(rp + 4);
            x[0] = v0.x; x[1] = v0.y; x[2] = v0.z; x[3] = v0.w;
            x[4] = v1.x; x[5] = v1.y; x[6] = v1.z; x[7] = v1.w;
        }
#pragma unroll
        for (int j = 0; j < 8; j++) {
            s[j] += x[j];
            ss[j] = fmaf(x[j], x[j], ss[j]);
        }
    }
#pragma unroll
    for (int j = 0; j < 8; j++) { lp[t][j] = s[j]; lq[t][j] = ss[j]; }
    __syncthreads();
    if (t < 64) {
        // dim d = t; partials live at threads r2*8 + (t>>3), entry (t&7)
        int o = t >> 3, j = t & 7;
        float a = 0.f, b = 0.f;
#pragma unroll 8
        for (int r2 = 0; r2 < 32; r2++) {
            a += lp[r2 * 8 + o][j];
            b += lq[r2 * 8 + o][j];
        }
        atomicAdd(&stats[t], a);
        atomicAdd(&stats[64 + t], b);
    }
}

// final BatchNorm -- r13: float4 vectorized (4 dims per thread per iter)
__global__ void bn_apply_kernel(float* __restrict__ h, const float* __restrict__ stats,
                                const float* __restrict__ g, const float* __restrict__ beta,
                                int n, int do_elu) {
    int i = blockIdx.x * blockDim.x + threadIdx.x;
    int total4 = n * 16;                 // n*64/4 float4s
    int stride = gridDim.x * blockDim.x;
    float invN = 1.f / (float)n;
    for (; i < total4; i += stride) {
        float4 v = ((const float4*)h)[i];
        int c0 = (i & 15) * 4;           // dims c0..c0+3
        float vv[4] = {v.x, v.y, v.z, v.w};
#pragma unroll
        for (int k = 0; k < 4; k++) {
            int c = c0 + k;
            float mu = stats[c] * invN;
            float var = fmaf(-mu, mu, stats[64 + c] * invN);
            float x = (vv[k] - mu) * rsqrtf(var + 1e-5f) * g[c] + beta[c];
            if (do_elu && x < 0.f) x = expm1f(x);
            vv[k] = x;
        }
        float4 o = {vv[0], vv[1], vv[2], vv[3]};
        ((float4*)h)[i] = o;
    }
}

// ---------------- launch ----------------

extern "C" void kernel_launch(void* const* d_in, const int* in_sizes, int n_in,
                              void* d_out, int out_size, void* d_ws, size_t ws_size,
                              hipStream_t stream) {
    const float* nw = (const float*)d_in[0];
    const int* src = (const int*)d_in[2];
    const int* dst = (const int*)d_in[3];
    const int N = in_sizes[0] / DIM;
    const int E = in_sizes[2];
    const float invN = 1.f / (float)N;
    const int nbuck = (N + BNODES - 1) >> BSHIFT;

    char* ws = (char*)d_ws;
    size_t off = 0;
    auto alloc = [&](size_t bytes) -> void* {
        void* p = ws + off;
        off += (bytes + 255) & ~(size_t)255;
        return p;
    };
    int* row_ptr      = (int*)alloc(((size_t)N + 1) * 4);
    int* bucket_cnt   = (int*)alloc(MAXB * 4);
    int* bucket_off   = (int*)alloc(MAXB * 4);
    int* bucket_fill  = (int*)alloc(MAXB * 4);
    int* hist         = (int*)alloc((size_t)MAXB * 256 * 4);   // per-block histograms
    unsigned long long* binned = (unsigned long long*)alloc((size_t)E * 8);
    int* src_sorted   = (int*)alloc((size_t)E * 4);
    float* el         = (float*)alloc((size_t)N * 4);
    float* er         = (float*)alloc((size_t)N * 4);
    __hip_bfloat16* feat = (__hip_bfloat16*)alloc((size_t)N * DIM * 2);
    __hip_bfloat16* hbuf = (__hip_bfloat16*)alloc((size_t)N * DIM * 2);  // bf16 intermediates
    float* stats      = (float*)alloc(3 * 512);     // 3 layer slots of 128 floats
    float* wlr        = (float*)alloc(3 * 128 * 4);
    short* wfrag      = (short*)alloc(3 * 8192 * 2); // [layer][hi/lo][4096] bf16

    int ntiles = (N + 15) >> 4;
    int attn_grid = (N + 15) / 16;
    if (attn_grid > 2048) attn_grid = 2048;   // persistent waves, grid-stride

    // prep: W frags + wl/wr + stats zero + per-block dst histograms (fused)
    prep_kernel<<<3 + 256, 256, 0, stream>>>(
        (const float*)d_in[4],  (const float*)d_in[5],  (const float*)d_in[6],
        (const float*)d_in[10], (const float*)d_in[11], (const float*)d_in[12],
        (const float*)d_in[16], (const float*)d_in[17], (const float*)d_in[18],
        wlr, wfrag, stats, dst, hist, E);
    bucket_scan_kernel<<<1, MAXB, 0, stream>>>(hist, bucket_cnt, bucket_off, bucket_fill);
    bin_scatter_kernel<<<(E + CHUNK - 1) / CHUNK, 256, 0, stream>>>(
        src, dst, bucket_off, bucket_fill, binned, E);
    csr_finalize_kernel<<<nbuck, 256, 0, stream>>>(binned, bucket_off, bucket_cnt,
                                                   row_ptr, src_sorted, N, E, nbuck);

    for (int l = 0; l < 3; l++) {
        const float* b    = (const float*)d_in[7 + 6 * l];
        const void* hin   = (l == 0) ? (const void*)nw : (const void*)hbuf;
        int in_bf16       = (l == 0) ? 0 : 1;
        void* hout        = (l == 2) ? (void*)d_out : (void*)hbuf;
        int out_bf16      = (l == 2) ? 0 : 1;
        float* stats_prev = (l == 0) ? stats : stats + (l - 1) * 128;
        float* stats_cur  = stats + l * 128;

        gemm64_mfma_kernel<<<(ntiles + 15) / 16, 256, 0, stream>>>(
            hin, in_bf16, wfrag + l * 8192,
            wlr + l * 128, wlr + l * 128 + 64,
            stats_prev,
            (l == 0) ? (const float*)d_in[8] : (const float*)d_in[8 + 6 * (l - 1)],
            (l == 0) ? (const float*)d_in[9] : (const float*)d_in[9 + 6 * (l - 1)],
            (l > 0) ? 1 : 0, invN,
            feat, el, er, N);
        attn_agg_kernel<<<attn_grid, 256, 0, stream>>>(row_ptr, src_sorted, el, er,
                                                       feat, b, hout, out_bf16, N);
        bn_stats_kernel<<<512, 256, 0, stream>>>(hout, out_bf16, stats_cur, N);
    }
    // final BatchNorm (no ELU) on d_out
    bn_apply_kernel<<<2048, 256, 0, stream>>>((float*)d_out, stats + 2 * 128,
                                              (const float*)d_in[8 + 12],
                                              (const float*)d_in[9 + 12],
                                              N, 0);
}